// Round 2
// baseline (454.346 us; speedup 1.0000x reference)
//
#include <hip/hip_runtime.h>
#include <hip/hip_bf16.h>

#define BATCH 8
#define SEQ   2048
#define DIM   768
#define HID   512

typedef __attribute__((ext_vector_type(8))) short  short8;
typedef __attribute__((ext_vector_type(4))) float  f32x4;

__device__ __forceinline__ unsigned short f2bf(float f) {
  union { float f; unsigned u; } x; x.f = f;
  return (unsigned short)((x.u + 0x7FFFu + ((x.u >> 16) & 1u)) >> 16);
}
__device__ __forceinline__ float bf2f(unsigned short u) {
  union { unsigned u; float f; } x; x.u = ((unsigned)u) << 16;
  return x.f;
}

// ---------------------------------------------------------------------------
// Templated bf16 MFMA GEMM, 128x128 tile, BK=32, 4 waves (2x2), 16x16x32 MFMA.
// All A/B staged f32 -> bf16 in LDS.
// VAR 0: fc1 gate  C=v@W1 (+b1, tanh, dot W2 -> per-row partials to pg)
// VAR 1: scores    C=(q@k^T)/sqrt(2048) -> bf16 packed in first half-bytes of
//                  each f32 weights row (ushort stride 4096)
// VAR 2: PV        C=weights@v + q -> f32 attn_output (A = f32 weights rows)
// ---------------------------------------------------------------------------
template<int VAR>
__global__ __launch_bounds__(256)
void mfma_gemm(const float* __restrict__ A, const float* __restrict__ Bf,
               const float* __restrict__ bias, const float* __restrict__ W2,
               float* __restrict__ pg, const float* __restrict__ qres,
               float* __restrict__ Cf)
{
  constexpr int K    = (VAR == 2) ? SEQ : DIM;
  constexpr int LDA  = (VAR == 2) ? SEQ : DIM;
  constexpr int LDBN = (VAR == 0) ? HID : DIM;   // B_KN leading dim

  __shared__ __align__(16) unsigned short As[128][40];  // +8 pad
  __shared__ __align__(16) unsigned short Bs[128][40];
  __shared__ float gred[128][2];

  const int tid  = threadIdx.x;
  const int z    = blockIdx.z;
  const int brow = blockIdx.y * 128;
  const int bcol = blockIdx.x * 128;

  const float* Az = A;
  const float* Bz = Bf;
  if constexpr (VAR == 1) {
    Az = A  + (size_t)z * SEQ * DIM;
    Bz = Bf + (size_t)z * SEQ * DIM;
  }
  if constexpr (VAR == 2) {
    Az = A  + (size_t)z * SEQ * SEQ;   // f32 weights
    Bz = Bf + (size_t)z * SEQ * DIM;
  }

  const int lane = tid & 63;
  const int wid  = tid >> 6;
  const int wr   = (wid >> 1) * 64;
  const int wc   = (wid & 1) * 64;
  const int lhi  = lane >> 4;   // 0..3
  const int llo  = lane & 15;   // 0..15

  f32x4 acc[4][4];
  #pragma unroll
  for (int m = 0; m < 4; ++m)
    #pragma unroll
    for (int n = 0; n < 4; ++n)
      acc[m][n] = (f32x4)(0.0f);

  for (int k0 = 0; k0 < K; k0 += 32) {
    // ---- stage A tile [128 rows x 32 k], f32 -> bf16
    #pragma unroll
    for (int i = 0; i < 4; ++i) {
      int idx = tid + i * 256;          // 0..1023
      int row = idx >> 3;               // 0..127
      int kg  = (idx & 7) << 2;         // 0..28
      float4 v4 = *reinterpret_cast<const float4*>(Az + (size_t)(brow + row) * LDA + (k0 + kg));
      ushort4 o; o.x = f2bf(v4.x); o.y = f2bf(v4.y); o.z = f2bf(v4.z); o.w = f2bf(v4.w);
      *reinterpret_cast<ushort4*>(&As[row][kg]) = o;
    }
    // ---- stage B tile -> Bs[n][k]
    if constexpr (VAR == 1) {
      // B = key rows [N x K]
      #pragma unroll
      for (int i = 0; i < 4; ++i) {
        int idx = tid + i * 256;
        int row = idx >> 3;
        int kg  = (idx & 7) << 2;
        float4 v4 = *reinterpret_cast<const float4*>(Bz + (size_t)(bcol + row) * DIM + (k0 + kg));
        ushort4 o; o.x = f2bf(v4.x); o.y = f2bf(v4.y); o.z = f2bf(v4.z); o.w = f2bf(v4.w);
        *reinterpret_cast<ushort4*>(&Bs[row][kg]) = o;
      }
    } else {
      // B [K x N]: coalesced float4 along N, transpose in registers
      int n4 = (tid & 31) << 2;         // 0..124
      int kb = (tid >> 5) << 2;         // 0..28
      float4 r0 = *reinterpret_cast<const float4*>(Bz + (size_t)(k0 + kb + 0) * LDBN + bcol + n4);
      float4 r1 = *reinterpret_cast<const float4*>(Bz + (size_t)(k0 + kb + 1) * LDBN + bcol + n4);
      float4 r2 = *reinterpret_cast<const float4*>(Bz + (size_t)(k0 + kb + 2) * LDBN + bcol + n4);
      float4 r3 = *reinterpret_cast<const float4*>(Bz + (size_t)(k0 + kb + 3) * LDBN + bcol + n4);
      ushort4 w0; w0.x = f2bf(r0.x); w0.y = f2bf(r1.x); w0.z = f2bf(r2.x); w0.w = f2bf(r3.x);
      ushort4 w1; w1.x = f2bf(r0.y); w1.y = f2bf(r1.y); w1.z = f2bf(r2.y); w1.w = f2bf(r3.y);
      ushort4 w2; w2.x = f2bf(r0.z); w2.y = f2bf(r1.z); w2.z = f2bf(r2.z); w2.w = f2bf(r3.z);
      ushort4 w3; w3.x = f2bf(r0.w); w3.y = f2bf(r1.w); w3.z = f2bf(r2.w); w3.w = f2bf(r3.w);
      *reinterpret_cast<ushort4*>(&Bs[n4 + 0][kb]) = w0;
      *reinterpret_cast<ushort4*>(&Bs[n4 + 1][kb]) = w1;
      *reinterpret_cast<ushort4*>(&Bs[n4 + 2][kb]) = w2;
      *reinterpret_cast<ushort4*>(&Bs[n4 + 3][kb]) = w3;
    }
    __syncthreads();

    short8 af[4], bfr[4];
    #pragma unroll
    for (int m = 0; m < 4; ++m)
      af[m] = *reinterpret_cast<const short8*>(&As[wr + m * 16 + llo][lhi * 8]);
    #pragma unroll
    for (int n = 0; n < 4; ++n)
      bfr[n] = *reinterpret_cast<const short8*>(&Bs[wc + n * 16 + llo][lhi * 8]);
    #pragma unroll
    for (int m = 0; m < 4; ++m)
      #pragma unroll
      for (int n = 0; n < 4; ++n)
        acc[m][n] = __builtin_amdgcn_mfma_f32_16x16x32_bf16(af[m], bfr[n], acc[m][n], 0, 0, 0);
    __syncthreads();
  }

  // ---- epilogues (C/D layout: col = lane&15, row = (lane>>4)*4 + r)
  if constexpr (VAR == 0) {
    #pragma unroll
    for (int m = 0; m < 4; ++m) {
      #pragma unroll
      for (int r = 0; r < 4; ++r) {
        int lrow = wr + m * 16 + lhi * 4 + r;
        float part = 0.f;
        #pragma unroll
        for (int n = 0; n < 4; ++n) {
          int colg = bcol + wc + n * 16 + llo;
          float t = tanhf(acc[m][n][r] + bias[colg]);
          part += t * W2[colg];
        }
        part += __shfl_xor(part, 1);
        part += __shfl_xor(part, 2);
        part += __shfl_xor(part, 4);
        part += __shfl_xor(part, 8);
        if (llo == 0) gred[lrow][wid & 1] = part;
      }
    }
    __syncthreads();
    if (tid < 128)
      pg[(size_t)blockIdx.x * 16384 + brow + tid] = gred[tid][0] + gred[tid][1];
  }
  if constexpr (VAR == 1) {
    const float rs = 0.02209708691207961f;  // 1/sqrt(2048)
    unsigned short* C16 = reinterpret_cast<unsigned short*>(Cf);
    #pragma unroll
    for (int m = 0; m < 4; ++m)
      #pragma unroll
      for (int r = 0; r < 4; ++r) {
        size_t R = (size_t)z * SEQ + (brow + wr + m * 16 + lhi * 4 + r);
        #pragma unroll
        for (int n = 0; n < 4; ++n) {
          int colg = bcol + wc + n * 16 + llo;
          C16[R * 4096 + colg] = f2bf(acc[m][n][r] * rs);
        }
      }
  }
  if constexpr (VAR == 2) {
    float* C = Cf + (size_t)z * SEQ * DIM;
    const float* Q = qres + (size_t)z * SEQ * DIM;
    #pragma unroll
    for (int m = 0; m < 4; ++m)
      #pragma unroll
      for (int r = 0; r < 4; ++r) {
        int rowg = brow + wr + m * 16 + lhi * 4 + r;
        #pragma unroll
        for (int n = 0; n < 4; ++n) {
          int colg = bcol + wc + n * 16 + llo;
          C[(size_t)rowg * DIM + colg] = acc[m][n][r] + Q[(size_t)rowg * DIM + colg];
        }
      }
  }
}

// g[row] = b2 + sum of 4 column-block partials (deterministic combine)
__global__ void g_combine(const float* __restrict__ pg, const float* __restrict__ b2,
                          float* __restrict__ g)
{
  int i = blockIdx.x * 256 + threadIdx.x;
  g[i] = b2[0] + pg[i] + pg[16384 + i] + pg[2 * 16384 + i] + pg[3 * 16384 + i];
}

// Column (axis=1 / query-axis) softmax stats over bf16 scores (ushort stride 4096)
__global__ __launch_bounds__(256)
void colstat_part(const unsigned short* __restrict__ sc, float* __restrict__ pm,
                  float* __restrict__ pl)
{
  const int gc = blockIdx.x * 256 + threadIdx.x;  // b*2048 + c
  const int b = gc >> 11;
  const int c = gc & 2047;
  const unsigned short* p = sc + (size_t)b * SEQ * 4096 + c;
  const int q0 = blockIdx.y * 128;
  float m = -1e30f;
  #pragma unroll 8
  for (int q = q0; q < q0 + 128; ++q) m = fmaxf(m, bf2f(p[(size_t)q * 4096]));
  float l = 0.f;
  #pragma unroll 8
  for (int q = q0; q < q0 + 128; ++q) l += __expf(bf2f(p[(size_t)q * 4096]) - m);
  pm[blockIdx.y * 16384 + gc] = m;
  pl[blockIdx.y * 16384 + gc] = l;
}

__global__ void colstat_comb(const float* __restrict__ pm, const float* __restrict__ pl,
                             float* __restrict__ mcol, float* __restrict__ lcol)
{
  int gc = blockIdx.x * 256 + threadIdx.x;
  float m = -1e30f;
  #pragma unroll
  for (int ch = 0; ch < 16; ++ch) m = fmaxf(m, pm[ch * 16384 + gc]);
  float l = 0.f;
  #pragma unroll
  for (int ch = 0; ch < 16; ++ch) l += pl[ch * 16384 + gc] * __expf(pm[ch * 16384 + gc] - m);
  mcol[gc] = m;
  lcol[gc] = l;
}

// Row pass: read own row's bf16 scores (first half-bytes of the f32 row slot),
// s = exp(x-m)/l; t = (s*(1-g) + g/S)/sqrt(768); row softmax; write f32 weights
// over the same row. All loads precede the block-wide __syncthreads, all stores
// follow it -> in-place safe.
__global__ __launch_bounds__(256)
void rowpass(float* __restrict__ w, const float* __restrict__ mcol,
             const float* __restrict__ lcol, const float* __restrict__ g)
{
  const size_t row = blockIdx.x;  // 0..16383 (= b*2048 + q)
  const int b = (int)(row >> 11);
  const unsigned short* p = reinterpret_cast<const unsigned short*>(w) + row * 4096;
  float* wrow = w + row * 2048;
  const int c0 = threadIdx.x * 8;
  const float* mc = mcol + (b << 11);
  const float* lc = lcol + (b << 11);
  const float* gb = g + (b << 11);

  unsigned short xs[8];
  *reinterpret_cast<ushort4*>(&xs[0]) = *reinterpret_cast<const ushort4*>(p + c0);
  *reinterpret_cast<ushort4*>(&xs[4]) = *reinterpret_cast<const ushort4*>(p + c0 + 4);
  float ms[8], ls[8], gs[8];
  *reinterpret_cast<float4*>(&ms[0]) = *reinterpret_cast<const float4*>(mc + c0);
  *reinterpret_cast<float4*>(&ms[4]) = *reinterpret_cast<const float4*>(mc + c0 + 4);
  *reinterpret_cast<float4*>(&ls[0]) = *reinterpret_cast<const float4*>(lc + c0);
  *reinterpret_cast<float4*>(&ls[4]) = *reinterpret_cast<const float4*>(lc + c0 + 4);
  *reinterpret_cast<float4*>(&gs[0]) = *reinterpret_cast<const float4*>(gb + c0);
  *reinterpret_cast<float4*>(&gs[4]) = *reinterpret_cast<const float4*>(gb + c0 + 4);

  float e[8];
  float psum = 0.f;
  #pragma unroll
  for (int j = 0; j < 8; ++j) {
    float x = bf2f(xs[j]);
    float s = __expf(x - ms[j]) / ls[j];
    float t = (s * (1.f - gs[j]) + gs[j] * (1.f / 2048.f)) * 0.03608439182435161f;
    float ev = __expf(t);
    e[j] = ev;
    psum += ev;
  }
  #pragma unroll
  for (int off = 1; off < 64; off <<= 1) psum += __shfl_xor(psum, off);
  __shared__ float red[4];
  if ((threadIdx.x & 63) == 0) red[threadIdx.x >> 6] = psum;
  __syncthreads();
  float inv = 1.f / (red[0] + red[1] + red[2] + red[3]);
  float4 o0, o1;
  o0.x = e[0] * inv; o0.y = e[1] * inv; o0.z = e[2] * inv; o0.w = e[3] * inv;
  o1.x = e[4] * inv; o1.y = e[5] * inv; o1.z = e[6] * inv; o1.w = e[7] * inv;
  *reinterpret_cast<float4*>(wrow + c0) = o0;
  *reinterpret_cast<float4*>(wrow + c0 + 4) = o1;
}

extern "C" void kernel_launch(void* const* d_in, const int* in_sizes, int n_in,
                              void* d_out, int out_size, void* d_ws, size_t ws_size,
                              hipStream_t stream)
{
  (void)in_sizes; (void)n_in; (void)out_size; (void)ws_size;
  const float* q  = (const float*)d_in[0];
  const float* k  = (const float*)d_in[1];
  const float* v  = (const float*)d_in[2];
  const float* W1 = (const float*)d_in[3];
  const float* b1 = (const float*)d_in[4];
  const float* W2 = (const float*)d_in[5];
  const float* b2 = (const float*)d_in[6];

  float* out0 = (float*)d_out;                       // [B,S,D] f32 attn_output
  float* wbuf = out0 + (size_t)BATCH * SEQ * DIM;    // [B,S,S] f32 attn_weights
                                                     // (bf16 scores packed in row half-bytes first)

  float* ws   = (float*)d_ws;   // 39*16384 floats = 2.56 MB
  float* g    = ws;             // 16384
  float* mcol = g + 16384;      // 16384
  float* lcol = mcol + 16384;   // 16384
  float* pg   = lcol + 16384;   // 4*16384
  float* pm   = pg + 4 * 16384; // 16*16384
  float* pl   = pm + 16 * 16384;// 16*16384

  // gate: fc1+tanh+W2 partial reduce, then deterministic combine
  mfma_gemm<0><<<dim3(4, 128, 1), 256, 0, stream>>>(v, W1, b1, W2, pg, nullptr, nullptr);
  g_combine<<<64, 256, 0, stream>>>(pg, b2, g);
  // scores -> bf16 packed into weights rows
  mfma_gemm<1><<<dim3(16, 16, 8), 256, 0, stream>>>(q, k, nullptr, nullptr, nullptr, nullptr, wbuf);
  // column (query-axis) softmax stats
  colstat_part<<<dim3(64, 16), 256, 0, stream>>>((const unsigned short*)wbuf, pm, pl);
  colstat_comb<<<64, 256, 0, stream>>>(pm, pl, mcol, lcol);
  // blend + row softmax, in place -> f32 attn_weights
  rowpass<<<16384, 256, 0, stream>>>(wbuf, mcol, lcol, g);
  // attn_output = weights @ v + q  (A = f32 weights)
  mfma_gemm<2><<<dim3(6, 16, 8), 256, 0, stream>>>(wbuf, v, nullptr, nullptr, nullptr, q, out0);
}

// Round 3
// 352.113 us; speedup vs baseline: 1.2903x; 1.2903x over previous
//
#include <hip/hip_runtime.h>

#define BATCH 8
#define SEQ   2048
#define DIM   768
#define HID   512

typedef __attribute__((ext_vector_type(8))) short  short8;
typedef __attribute__((ext_vector_type(4))) float  f32x4;

__device__ __forceinline__ unsigned short f2bf(float f) {
  union { float f; unsigned u; } x; x.f = f;
  return (unsigned short)((x.u + 0x7FFFu + ((x.u >> 16) & 1u)) >> 16);
}
__device__ __forceinline__ float bf2f(unsigned short u) {
  union { unsigned u; float f; } x; x.u = ((unsigned)u) << 16;
  return x.f;
}
__device__ __forceinline__ void gll16(const void* g, void* l) {
  __builtin_amdgcn_global_load_lds(
      (const __attribute__((address_space(1))) void*)g,
      (__attribute__((address_space(3))) void*)l, 16, 0, 0);
}
// XOR swizzles (involutions; keep bits 0-3, so 16B chunks stay contiguous)
__device__ __forceinline__ int swz2(int o) { return o ^ (((o >> 8) & 7) << 4); }  // bf16, 64B rows
__device__ __forceinline__ int swz3(int o) { return o ^ (((o >> 7) & 7) << 4); }  // f32, 128B rows

// ---------------------------------------------------------------------------
// bf16 MFMA GEMM, 128x128 tile, BK=32, 4 waves (2x2), 16x16x32 MFMA.
// Staging via global_load_lds(16B) from pre-converted bf16, swizzled LDS.
// VAR 0: gate   A=vb(slot-packed,pitch4096) B=W1T(pitch768)  K=768 -> pg
// VAR 1: scores A=qb(pitch768)  B=kb(slot-packed,pitch4096)  K=768 -> bf16 scores
// VAR 2 FAST:   A=wb(pitch2048) B=vT(pitch2048)              K=2048 -> out+q
// VAR 2 slow:   A=f32 weights (gll f32 + truncate at frag-load),
//               B=f32 v reg-transpose-truncate (swizzled ds_write)
// ---------------------------------------------------------------------------
template<int VAR, bool FAST>
__global__ __launch_bounds__(256)
void mfma_gemm(const unsigned short* __restrict__ Ab, const unsigned short* __restrict__ Bb,
               const float* __restrict__ Af32, const float* __restrict__ Bf32,
               const float* __restrict__ bias, const float* __restrict__ W2,
               float* __restrict__ pg, const float* __restrict__ qres,
               float* __restrict__ Cf)
{
  constexpr int  K      = (VAR == 2) ? SEQ : DIM;
  constexpr int  APITCH = (VAR == 0) ? 4096 : (VAR == 1 ? DIM : SEQ);
  constexpr int  BPITCH = (VAR == 0) ? DIM  : (VAR == 1 ? 4096 : SEQ);
  constexpr bool SLOWA  = (VAR == 2) && !FAST;
  constexpr bool SLOWB  = (VAR == 2) && !FAST;

  __shared__ __align__(16) unsigned short AsL[128 * (SLOWA ? 64 : 32)];
  __shared__ __align__(16) unsigned short BsL[128 * 32];
  __shared__ float gred[128][2];

  const int tid  = threadIdx.x;
  const int z    = blockIdx.z;
  const int brow = blockIdx.y * 128;
  const int bcol = blockIdx.x * 128;
  const int lane = tid & 63;
  const int wid  = tid >> 6;
  const int wr   = (wid >> 1) * 64;
  const int wc   = (wid & 1) * 64;
  const int lhi  = lane >> 4;
  const int llo  = lane & 15;

  const unsigned short* Asrc = Ab;
  const unsigned short* Bsrc = Bb;
  const float* AsrcF = Af32;
  const float* BsrcF = Bf32;
  if constexpr (VAR == 1) { Asrc += (size_t)z * SEQ * DIM; Bsrc += (size_t)z * SEQ * 4096; }
  if constexpr (VAR == 2) {
    if constexpr (FAST) { Asrc += (size_t)z * SEQ * SEQ; Bsrc += (size_t)z * DIM * SEQ; }
    else                { AsrcF += (size_t)z * SEQ * SEQ; BsrcF += (size_t)z * SEQ * DIM; }
  }
  if constexpr (!SLOWA) Asrc += (size_t)brow * APITCH;
  else                  AsrcF += (size_t)brow * SEQ;
  if constexpr (!SLOWB) Bsrc += (size_t)bcol * BPITCH;

  f32x4 acc[4][4];
  #pragma unroll
  for (int m = 0; m < 4; ++m)
    #pragma unroll
    for (int n = 0; n < 4; ++n)
      acc[m][n] = (f32x4)(0.0f);

  for (int k0 = 0; k0 < K; k0 += 32) {
    // ---- stage A
    if constexpr (!SLOWA) {
      #pragma unroll
      for (int i = 0; i < 2; ++i) {
        int ob = wid * 2048 + i * 1024;
        int o  = ob + lane * 16;
        int a  = swz2(o);
        gll16((const char*)Asrc + (size_t)(a >> 6) * (APITCH * 2) + (size_t)k0 * 2 + (a & 63),
              (char*)AsL + ob);
      }
    } else {
      #pragma unroll
      for (int i = 0; i < 4; ++i) {
        int ob = wid * 4096 + i * 1024;
        int o  = ob + lane * 16;
        int a  = swz3(o);
        gll16((const char*)AsrcF + (size_t)(a >> 7) * (SEQ * 4) + (size_t)k0 * 4 + (a & 127),
              (char*)AsL + ob);
      }
    }
    // ---- stage B
    if constexpr (!SLOWB) {
      #pragma unroll
      for (int i = 0; i < 2; ++i) {
        int ob = wid * 2048 + i * 1024;
        int o  = ob + lane * 16;
        int a  = swz2(o);
        gll16((const char*)Bsrc + (size_t)(a >> 6) * (BPITCH * 2) + (size_t)k0 * 2 + (a & 63),
              (char*)BsL + ob);
      }
    } else {
      int n4 = (tid & 31) << 2;
      int kb = (tid >> 5) << 2;
      float4 r0 = *(const float4*)(BsrcF + (size_t)(k0 + kb + 0) * DIM + bcol + n4);
      float4 r1 = *(const float4*)(BsrcF + (size_t)(k0 + kb + 1) * DIM + bcol + n4);
      float4 r2 = *(const float4*)(BsrcF + (size_t)(k0 + kb + 2) * DIM + bcol + n4);
      float4 r3 = *(const float4*)(BsrcF + (size_t)(k0 + kb + 3) * DIM + bcol + n4);
      float a0[4] = {r0.x, r0.y, r0.z, r0.w};
      float a1[4] = {r1.x, r1.y, r1.z, r1.w};
      float a2[4] = {r2.x, r2.y, r2.z, r2.w};
      float a3[4] = {r3.x, r3.y, r3.z, r3.w};
      #pragma unroll
      for (int jj = 0; jj < 4; ++jj) {
        unsigned lo = (__float_as_uint(a0[jj]) >> 16) | (__float_as_uint(a1[jj]) & 0xFFFF0000u);
        unsigned hi = (__float_as_uint(a2[jj]) >> 16) | (__float_as_uint(a3[jj]) & 0xFFFF0000u);
        int ol = (n4 + jj) * 64 + kb * 2;
        *(uint2*)((char*)BsL + swz2(ol)) = make_uint2(lo, hi);
      }
    }
    __syncthreads();

    short8 af[4], bfr[4];
    #pragma unroll
    for (int m = 0; m < 4; ++m) {
      int row = wr + m * 16 + llo;
      if constexpr (!SLOWA) {
        int a = row * 64 + lhi * 16;
        af[m] = *(const short8*)((const char*)AsL + swz2(a));
      } else {
        int a0i = row * 128 + lhi * 32;
        int a1i = a0i + 16;
        f32x4 x = *(const f32x4*)((const char*)AsL + swz3(a0i));
        f32x4 y = *(const f32x4*)((const char*)AsL + swz3(a1i));
        union { unsigned u[4]; short8 s; } r;
        r.u[0] = (__float_as_uint(x[0]) >> 16) | (__float_as_uint(x[1]) & 0xFFFF0000u);
        r.u[1] = (__float_as_uint(x[2]) >> 16) | (__float_as_uint(x[3]) & 0xFFFF0000u);
        r.u[2] = (__float_as_uint(y[0]) >> 16) | (__float_as_uint(y[1]) & 0xFFFF0000u);
        r.u[3] = (__float_as_uint(y[2]) >> 16) | (__float_as_uint(y[3]) & 0xFFFF0000u);
        af[m] = r.s;
      }
    }
    #pragma unroll
    for (int n = 0; n < 4; ++n) {
      int row = wc + n * 16 + llo;
      int a = row * 64 + lhi * 16;
      bfr[n] = *(const short8*)((const char*)BsL + swz2(a));
    }
    #pragma unroll
    for (int m = 0; m < 4; ++m)
      #pragma unroll
      for (int n = 0; n < 4; ++n)
        acc[m][n] = __builtin_amdgcn_mfma_f32_16x16x32_bf16(af[m], bfr[n], acc[m][n], 0, 0, 0);
    __syncthreads();
  }

  // ---- epilogues (C/D: col = lane&15, row = (lane>>4)*4 + r)
  if constexpr (VAR == 0) {
    #pragma unroll
    for (int m = 0; m < 4; ++m) {
      #pragma unroll
      for (int r = 0; r < 4; ++r) {
        int lrow = wr + m * 16 + lhi * 4 + r;
        float part = 0.f;
        #pragma unroll
        for (int n = 0; n < 4; ++n) {
          int colg = bcol + wc + n * 16 + llo;
          float t = tanhf(acc[m][n][r] + bias[colg]);
          part += t * W2[colg];
        }
        part += __shfl_xor(part, 1);
        part += __shfl_xor(part, 2);
        part += __shfl_xor(part, 4);
        part += __shfl_xor(part, 8);
        if (llo == 0) gred[lrow][wid & 1] = part;
      }
    }
    __syncthreads();
    if (tid < 128)
      pg[(size_t)blockIdx.x * 16384 + brow + tid] = gred[tid][0] + gred[tid][1];
  }
  if constexpr (VAR == 1) {
    const float rs = 0.02209708691207961f;  // 1/sqrt(2048)
    unsigned short* C16 = reinterpret_cast<unsigned short*>(Cf);
    #pragma unroll
    for (int m = 0; m < 4; ++m)
      #pragma unroll
      for (int r = 0; r < 4; ++r) {
        size_t R = (size_t)z * SEQ + (brow + wr + m * 16 + lhi * 4 + r);
        #pragma unroll
        for (int n = 0; n < 4; ++n) {
          int colg = bcol + wc + n * 16 + llo;
          C16[R * 4096 + colg] = f2bf(acc[m][n][r] * rs);
        }
      }
  }
  if constexpr (VAR == 2) {
    float* C = Cf + (size_t)z * SEQ * DIM;
    const float* Q = qres + (size_t)z * SEQ * DIM;
    #pragma unroll
    for (int m = 0; m < 4; ++m)
      #pragma unroll
      for (int r = 0; r < 4; ++r) {
        int rowg = brow + wr + m * 16 + lhi * 4 + r;
        #pragma unroll
        for (int n = 0; n < 4; ++n) {
          int colg = bcol + wc + n * 16 + llo;
          C[(size_t)rowg * DIM + colg] = acc[m][n][r] + Q[(size_t)rowg * DIM + colg];
        }
      }
  }
}

// q,k,v f32 -> bf16 (RN). qb contiguous (out0 region); kb/vb into the upper
// 2048-ushort half of each weights-row slot (free until rowpass).
__global__ __launch_bounds__(256)
void prepack(const float* __restrict__ q, const float* __restrict__ k,
             const float* __restrict__ v, unsigned short* __restrict__ qb,
             unsigned short* __restrict__ wsl)
{
  const int NT = (BATCH * SEQ * DIM) / 4;  // 3,145,728 quads
  for (int i = blockIdx.x * 256 + threadIdx.x; i < NT; i += 2048 * 256) {
    int e = i * 4;
    float4 qv = *(const float4*)(q + e);
    float4 kv = *(const float4*)(k + e);
    float4 vv = *(const float4*)(v + e);
    ushort4 qo; qo.x = f2bf(qv.x); qo.y = f2bf(qv.y); qo.z = f2bf(qv.z); qo.w = f2bf(qv.w);
    ushort4 ko; ko.x = f2bf(kv.x); ko.y = f2bf(kv.y); ko.z = f2bf(kv.z); ko.w = f2bf(kv.w);
    ushort4 vo; vo.x = f2bf(vv.x); vo.y = f2bf(vv.y); vo.z = f2bf(vv.z); vo.w = f2bf(vv.w);
    *(ushort4*)(qb + e) = qo;
    int r = e / DIM, c = e % DIM;
    size_t off = (size_t)r * 4096 + 2048 + c;
    *(ushort4*)(wsl + off) = ko;
    *(ushort4*)(wsl + off + DIM) = vo;
  }
}

// [R][C] f32 -> [C][R] bf16 (RN), 64x64 LDS tiles, batched via blockIdx.z
__global__ __launch_bounds__(256)
void transpose_f32_bf16(const float* __restrict__ src, unsigned short* __restrict__ dst,
                        int R, int C)
{
  __shared__ unsigned short T[64][65];
  const float* s = src + (size_t)blockIdx.z * R * C;
  unsigned short* d = dst + (size_t)blockIdx.z * R * C;
  int r0 = blockIdx.y * 64, c0 = blockIdx.x * 64;
  int tr = threadIdx.x >> 6, tc = threadIdx.x & 63;
  #pragma unroll
  for (int j = 0; j < 16; ++j) {
    int row = j * 4 + tr;
    T[row][tc] = f2bf(s[(size_t)(r0 + row) * C + c0 + tc]);
  }
  __syncthreads();
  #pragma unroll
  for (int j = 0; j < 16; ++j) {
    int row = j * 4 + tr;
    d[(size_t)(c0 + row) * R + r0 + tc] = T[tc][row];
  }
}

__global__ void g_combine(const float* __restrict__ pg, const float* __restrict__ b2,
                          float* __restrict__ g)
{
  int i = blockIdx.x * 256 + threadIdx.x;
  g[i] = b2[0] + pg[i] + pg[16384 + i] + pg[2 * 16384 + i] + pg[3 * 16384 + i];
}

// Column (query-axis) sum of exp — max-free (|score| <= ~4, no overflow risk)
__global__ __launch_bounds__(256)
void colstat_part(const unsigned short* __restrict__ sc, float* __restrict__ pl)
{
  const int gc = blockIdx.x * 256 + threadIdx.x;
  const int b = gc >> 11, c = gc & 2047;
  const unsigned short* p = sc + (size_t)b * SEQ * 4096 + c;
  const int q0 = blockIdx.y * 128;
  float l = 0.f;
  #pragma unroll 4
  for (int qq = q0; qq < q0 + 128; ++qq) l += __expf(bf2f(p[(size_t)qq * 4096]));
  pl[blockIdx.y * 16384 + gc] = l;
}

__global__ void colstat_comb(const float* __restrict__ pl, float* __restrict__ lcol)
{
  int gc = blockIdx.x * 256 + threadIdx.x;
  float l = 0.f;
  #pragma unroll
  for (int ch = 0; ch < 16; ++ch) l += pl[ch * 16384 + gc];
  lcol[gc] = l;
}

// Row pass: s = exp(x)/lcol; t = (s*(1-g) + g/S)/sqrt(768); row softmax.
// In-place bf16->f32; optional bf16 weights copy (FAST tier).
template<bool FAST>
__global__ __launch_bounds__(256)
void rowpass(float* __restrict__ w, const float* __restrict__ lcol,
             const float* __restrict__ gg, unsigned short* __restrict__ wb)
{
  const size_t row = blockIdx.x;
  const int b = (int)(row >> 11);
  const unsigned short* p = (const unsigned short*)w + row * 4096;
  float* wrow = w + row * 2048;
  const int c0 = threadIdx.x * 8;
  const float* lc = lcol + (b << 11);
  const float* gb = gg + (b << 11);

  unsigned short xs[8];
  *(ushort4*)&xs[0] = *(const ushort4*)(p + c0);
  *(ushort4*)&xs[4] = *(const ushort4*)(p + c0 + 4);
  float ls[8], gs[8];
  *(float4*)&ls[0] = *(const float4*)(lc + c0);
  *(float4*)&ls[4] = *(const float4*)(lc + c0 + 4);
  *(float4*)&gs[0] = *(const float4*)(gb + c0);
  *(float4*)&gs[4] = *(const float4*)(gb + c0 + 4);

  float e[8];
  float psum = 0.f;
  #pragma unroll
  for (int j = 0; j < 8; ++j) {
    float s = __expf(bf2f(xs[j])) / ls[j];
    float t = (s * (1.f - gs[j]) + gs[j] * (1.f / 2048.f)) * 0.03608439182435161f;
    float ev = __expf(t);
    e[j] = ev;
    psum += ev;
  }
  #pragma unroll
  for (int off = 1; off < 64; off <<= 1) psum += __shfl_xor(psum, off);
  __shared__ float red[4];
  if ((threadIdx.x & 63) == 0) red[threadIdx.x >> 6] = psum;
  __syncthreads();
  float inv = 1.f / (red[0] + red[1] + red[2] + red[3]);
  float4 o0, o1;
  o0.x = e[0] * inv; o0.y = e[1] * inv; o0.z = e[2] * inv; o0.w = e[3] * inv;
  o1.x = e[4] * inv; o1.y = e[5] * inv; o1.z = e[6] * inv; o1.w = e[7] * inv;
  *(float4*)(wrow + c0) = o0;
  *(float4*)(wrow + c0 + 4) = o1;
  if constexpr (FAST) {
    ushort4 b0, b1v;
    b0.x = f2bf(o0.x); b0.y = f2bf(o0.y); b0.z = f2bf(o0.z); b0.w = f2bf(o0.w);
    b1v.x = f2bf(o1.x); b1v.y = f2bf(o1.y); b1v.z = f2bf(o1.z); b1v.w = f2bf(o1.w);
    *(ushort4*)(wb + row * 2048 + c0) = b0;
    *(ushort4*)(wb + row * 2048 + c0 + 4) = b1v;
  }
}

extern "C" void kernel_launch(void* const* d_in, const int* in_sizes, int n_in,
                              void* d_out, int out_size, void* d_ws, size_t ws_size,
                              hipStream_t stream)
{
  (void)in_sizes; (void)n_in; (void)out_size;
  const float* q  = (const float*)d_in[0];
  const float* k  = (const float*)d_in[1];
  const float* v  = (const float*)d_in[2];
  const float* W1 = (const float*)d_in[3];
  const float* b1 = (const float*)d_in[4];
  const float* W2 = (const float*)d_in[5];
  const float* b2 = (const float*)d_in[6];

  float* out0 = (float*)d_out;                       // [B,S,D] f32 (also holds qb until VAR2)
  float* wbuf = out0 + (size_t)BATCH * SEQ * DIM;    // [B,S,S] f32 weights slots
  unsigned short* wsl = (unsigned short*)wbuf;       // slot view (lower: scores, upper: kb/vb)
  unsigned short* qb  = (unsigned short*)out0;

  float* g    = (float*)d_ws;                        // 16384
  float* lcol = g + 16384;                           // 16384
  float* pg   = lcol + 16384;                        // 65536
  float* pl   = pg + 65536;                          // 262144
  unsigned short* W1T = (unsigned short*)(pl + 262144);            // 393216 ushorts
  unsigned short* vT  = (unsigned short*)((char*)d_ws + 2228224);  // 12.58M ushorts
  unsigned short* wb  = vT + (size_t)12582912;                     // 33.55M ushorts
  const bool fast = ws_size >= 94502912ull;

  prepack<<<2048, 256, 0, stream>>>(q, k, v, qb, wsl);
  transpose_f32_bf16<<<dim3(8, 12, 1), 256, 0, stream>>>(W1, W1T, 768, 512);
  if (fast)
    transpose_f32_bf16<<<dim3(12, 32, 8), 256, 0, stream>>>(v, vT, 2048, 768);

  mfma_gemm<0, false><<<dim3(4, 128, 1), 256, 0, stream>>>(
      wsl + 2816, W1T, nullptr, nullptr, b1, W2, pg, nullptr, nullptr);
  g_combine<<<64, 256, 0, stream>>>(pg, b2, g);

  mfma_gemm<1, false><<<dim3(16, 16, 8), 256, 0, stream>>>(
      qb, wsl + 2048, nullptr, nullptr, nullptr, nullptr, nullptr, nullptr, wbuf);

  colstat_part<<<dim3(64, 16), 256, 0, stream>>>(wsl, pl);
  colstat_comb<<<64, 256, 0, stream>>>(pl, lcol);

  if (fast) {
    rowpass<true><<<16384, 256, 0, stream>>>(wbuf, lcol, g, wb);
    mfma_gemm<2, true><<<dim3(6, 16, 8), 256, 0, stream>>>(
        wb, vT, nullptr, nullptr, nullptr, nullptr, nullptr, q, out0);
  } else {
    rowpass<false><<<16384, 256, 0, stream>>>(wbuf, lcol, g, nullptr);
    mfma_gemm<2, false><<<dim3(6, 16, 8), 256, 0, stream>>>(
        nullptr, nullptr, wbuf, v, nullptr, nullptr, nullptr, q, out0);
  }
}

// Round 4
// 311.239 us; speedup vs baseline: 1.4598x; 1.1313x over previous
//
#include <hip/hip_runtime.h>

#define BATCH 8
#define SEQ   2048
#define DIM   768
#define HID   512

typedef __attribute__((ext_vector_type(8))) short  short8;
typedef __attribute__((ext_vector_type(4))) float  f32x4;

__device__ __forceinline__ unsigned short f2bf(float f) {
  union { float f; unsigned u; } x; x.f = f;
  return (unsigned short)((x.u + 0x7FFFu + ((x.u >> 16) & 1u)) >> 16);
}
__device__ __forceinline__ float bf2f(unsigned short u) {
  union { unsigned u; float f; } x; x.u = ((unsigned)u) << 16;
  return x.f;
}
__device__ __forceinline__ void gll16(const void* g, void* l) {
  __builtin_amdgcn_global_load_lds(
      (const __attribute__((address_space(1))) void*)g,
      (__attribute__((address_space(3))) void*)l, 16, 0, 0);
}
// XOR swizzles (involutions; keep bits 0-3 so 16B chunks stay contiguous)
__device__ __forceinline__ int swz2(int o) { return o ^ (((o >> 8) & 7) << 4); }  // bf16, 64B rows
__device__ __forceinline__ int swz3(int o) { return o ^ (((o >> 7) & 7) << 4); }  // f32, 128B rows

// ---------------------------------------------------------------------------
// Double-buffered bf16 MFMA GEMM, 128x128 tile, BK=32, 4 waves (2x2).
// Prefetch next K-tile via global_load_lds while computing current; counted
// s_waitcnt vmcnt(4) (4 gll/wave/tile in flight) + raw s_barrier — no vmcnt(0)
// drain in the main loop. XCD-swizzled 1D grid (all grids divisible by 8).
// VAR 0: gate   A=vb(slots,pitch4096) B=W1T(pitch768)  K=768, grid 4x128
// VAR 1: scores A=qb(pitch768) B=kb(slots,pitch4096)   K=768, grid 16x16x8
// VAR 2: PV     A=wb(pitch2048) B=vT(pitch2048)        K=2048, grid 6x16x8
// ---------------------------------------------------------------------------
template<int VAR>
__global__ __launch_bounds__(256)
void gemm_db(const unsigned short* __restrict__ Ab, const unsigned short* __restrict__ Bb,
             const float* __restrict__ bias, const float* __restrict__ W2,
             float* __restrict__ pg, const float* __restrict__ qres,
             float* __restrict__ Cf)
{
  constexpr int K      = (VAR == 2) ? SEQ : DIM;
  constexpr int NT     = K / 32;
  constexpr int APITCH = (VAR == 0) ? 4096 : (VAR == 1 ? DIM : SEQ);
  constexpr int BPITCH = (VAR == 0) ? DIM  : (VAR == 1 ? 4096 : SEQ);
  constexpr int GX     = (VAR == 0) ? 4 : (VAR == 1 ? 16 : 6);
  constexpr int GY     = (VAR == 0) ? 128 : 16;
  constexpr int NWG    = GX * GY * ((VAR == 0) ? 1 : 8);

  __shared__ __align__(16) unsigned short AsL[2 * 128 * 32];
  __shared__ __align__(16) unsigned short BsL[2 * 128 * 32];
  __shared__ float gred[(VAR == 0) ? 128 : 1][2];

  // bijective XCD swizzle (NWG % 8 == 0)
  int wg = blockIdx.x;
  wg = (wg & 7) * (NWG >> 3) + (wg >> 3);
  const int bx = wg % GX;
  const int by = (wg / GX) % GY;
  const int z  = wg / (GX * GY);

  const int tid  = threadIdx.x;
  const int brow = by * 128;
  const int bcol = bx * 128;
  const int lane = tid & 63;
  const int wid  = tid >> 6;
  const int wr   = (wid >> 1) * 64;
  const int wc   = (wid & 1) * 64;
  const int lhi  = lane >> 4;
  const int llo  = lane & 15;

  const unsigned short* Asrc = Ab;
  const unsigned short* Bsrc = Bb;
  if constexpr (VAR == 1) { Asrc += (size_t)z * SEQ * DIM; Bsrc += (size_t)z * SEQ * 4096; }
  if constexpr (VAR == 2) { Asrc += (size_t)z * SEQ * SEQ; Bsrc += (size_t)z * DIM * SEQ; }
  Asrc += (size_t)brow * APITCH;
  Bsrc += (size_t)bcol * BPITCH;

  f32x4 acc[4][4];
  #pragma unroll
  for (int m = 0; m < 4; ++m)
    #pragma unroll
    for (int n = 0; n < 4; ++n)
      acc[m][n] = (f32x4)(0.0f);

  auto stage = [&](int buf, int k0) {
    #pragma unroll
    for (int i = 0; i < 2; ++i) {
      int ob = wid * 2048 + i * 1024;
      int o  = ob + lane * 16;
      int a  = swz2(o);
      gll16((const char*)Asrc + (size_t)(a >> 6) * (APITCH * 2) + (size_t)k0 * 2 + (a & 63),
            (char*)AsL + buf * 8192 + ob);
    }
    #pragma unroll
    for (int i = 0; i < 2; ++i) {
      int ob = wid * 2048 + i * 1024;
      int o  = ob + lane * 16;
      int a  = swz2(o);
      gll16((const char*)Bsrc + (size_t)(a >> 6) * (BPITCH * 2) + (size_t)k0 * 2 + (a & 63),
            (char*)BsL + buf * 8192 + ob);
    }
  };

  stage(0, 0);
  for (int t = 0; t < NT; ++t) {
    if (t + 1 < NT) {
      stage((t + 1) & 1, (t + 1) * 32);
      asm volatile("s_waitcnt vmcnt(4)" ::: "memory");
    } else {
      asm volatile("s_waitcnt vmcnt(0)" ::: "memory");
    }
    __builtin_amdgcn_s_barrier();
    __builtin_amdgcn_sched_barrier(0);

    const int bb = (t & 1) * 8192;
    short8 af[4], bfr[4];
    #pragma unroll
    for (int m = 0; m < 4; ++m) {
      int a = (wr + m * 16 + llo) * 64 + lhi * 16;
      af[m] = *(const short8*)((const char*)AsL + bb + swz2(a));
    }
    #pragma unroll
    for (int n = 0; n < 4; ++n) {
      int a = (wc + n * 16 + llo) * 64 + lhi * 16;
      bfr[n] = *(const short8*)((const char*)BsL + bb + swz2(a));
    }
    #pragma unroll
    for (int m = 0; m < 4; ++m)
      #pragma unroll
      for (int n = 0; n < 4; ++n)
        acc[m][n] = __builtin_amdgcn_mfma_f32_16x16x32_bf16(af[m], bfr[n], acc[m][n], 0, 0, 0);

    __builtin_amdgcn_sched_barrier(0);
    __builtin_amdgcn_s_barrier();
    __builtin_amdgcn_sched_barrier(0);
  }

  // ---- epilogues (C/D: col = lane&15, row = (lane>>4)*4 + r)
  if constexpr (VAR == 0) {
    #pragma unroll
    for (int m = 0; m < 4; ++m) {
      #pragma unroll
      for (int r = 0; r < 4; ++r) {
        int lrow = wr + m * 16 + lhi * 4 + r;
        float part = 0.f;
        #pragma unroll
        for (int n = 0; n < 4; ++n) {
          int colg = bcol + wc + n * 16 + llo;
          float t = tanhf(acc[m][n][r] + bias[colg]);
          part += t * W2[colg];
        }
        part += __shfl_xor(part, 1);
        part += __shfl_xor(part, 2);
        part += __shfl_xor(part, 4);
        part += __shfl_xor(part, 8);
        if (llo == 0) gred[lrow][wid & 1] = part;
      }
    }
    __syncthreads();
    if (tid < 128)
      pg[(size_t)bx * 16384 + brow + tid] = gred[tid][0] + gred[tid][1];
  }
  if constexpr (VAR == 1) {
    const float rs = 0.02209708691207961f;  // 1/sqrt(2048)
    unsigned short* C16 = reinterpret_cast<unsigned short*>(Cf);
    #pragma unroll
    for (int m = 0; m < 4; ++m)
      #pragma unroll
      for (int r = 0; r < 4; ++r) {
        size_t R = (size_t)z * SEQ + (brow + wr + m * 16 + lhi * 4 + r);
        #pragma unroll
        for (int n = 0; n < 4; ++n) {
          int colg = bcol + wc + n * 16 + llo;
          C16[R * 4096 + colg] = f2bf(acc[m][n][r] * rs);
        }
      }
  }
  if constexpr (VAR == 2) {
    float* C = Cf + (size_t)z * SEQ * DIM;
    const float* Q = qres + (size_t)z * SEQ * DIM;
    #pragma unroll
    for (int m = 0; m < 4; ++m)
      #pragma unroll
      for (int r = 0; r < 4; ++r) {
        int rowg = brow + wr + m * 16 + lhi * 4 + r;
        #pragma unroll
        for (int n = 0; n < 4; ++n) {
          int colg = bcol + wc + n * 16 + llo;
          C[(size_t)rowg * DIM + colg] = acc[m][n][r] + Q[(size_t)rowg * DIM + colg];
        }
      }
  }
}

// ---------------------------------------------------------------------------
// Fallback PV GEMM (f32 weights + f32 v), single-buffer — only if ws too small.
// ---------------------------------------------------------------------------
__global__ __launch_bounds__(256)
void gemm_slow(const float* __restrict__ Wf, const float* __restrict__ Vf,
               const float* __restrict__ qres, float* __restrict__ Cf)
{
  __shared__ __align__(16) unsigned short AsL[128 * 64];
  __shared__ __align__(16) unsigned short BsL[128 * 32];

  const int tid  = threadIdx.x;
  const int z    = blockIdx.z;
  const int brow = blockIdx.y * 128;
  const int bcol = blockIdx.x * 128;
  const int lane = tid & 63;
  const int wid  = tid >> 6;
  const int wr   = (wid >> 1) * 64;
  const int wc   = (wid & 1) * 64;
  const int lhi  = lane >> 4;
  const int llo  = lane & 15;

  const float* AsrcF = Wf + (size_t)z * SEQ * SEQ + (size_t)brow * SEQ;
  const float* BsrcF = Vf + (size_t)z * SEQ * DIM;

  f32x4 acc[4][4];
  #pragma unroll
  for (int m = 0; m < 4; ++m)
    #pragma unroll
    for (int n = 0; n < 4; ++n)
      acc[m][n] = (f32x4)(0.0f);

  for (int k0 = 0; k0 < SEQ; k0 += 32) {
    #pragma unroll
    for (int i = 0; i < 4; ++i) {
      int ob = wid * 4096 + i * 1024;
      int o  = ob + lane * 16;
      int a  = swz3(o);
      gll16((const char*)AsrcF + (size_t)(a >> 7) * (SEQ * 4) + (size_t)k0 * 4 + (a & 127),
            (char*)AsL + ob);
    }
    {
      int n4 = (tid & 31) << 2;
      int kb = (tid >> 5) << 2;
      float4 r0 = *(const float4*)(BsrcF + (size_t)(k0 + kb + 0) * DIM + bcol + n4);
      float4 r1 = *(const float4*)(BsrcF + (size_t)(k0 + kb + 1) * DIM + bcol + n4);
      float4 r2 = *(const float4*)(BsrcF + (size_t)(k0 + kb + 2) * DIM + bcol + n4);
      float4 r3 = *(const float4*)(BsrcF + (size_t)(k0 + kb + 3) * DIM + bcol + n4);
      float a0[4] = {r0.x, r0.y, r0.z, r0.w};
      float a1[4] = {r1.x, r1.y, r1.z, r1.w};
      float a2[4] = {r2.x, r2.y, r2.z, r2.w};
      float a3[4] = {r3.x, r3.y, r3.z, r3.w};
      #pragma unroll
      for (int jj = 0; jj < 4; ++jj) {
        unsigned lo = (__float_as_uint(a0[jj]) >> 16) | (__float_as_uint(a1[jj]) & 0xFFFF0000u);
        unsigned hi = (__float_as_uint(a2[jj]) >> 16) | (__float_as_uint(a3[jj]) & 0xFFFF0000u);
        int ol = (n4 + jj) * 64 + kb * 2;
        *(uint2*)((char*)BsL + swz2(ol)) = make_uint2(lo, hi);
      }
    }
    __syncthreads();

    short8 af[4], bfr[4];
    #pragma unroll
    for (int m = 0; m < 4; ++m) {
      int row = wr + m * 16 + llo;
      int a0i = row * 128 + lhi * 32;
      f32x4 x = *(const f32x4*)((const char*)AsL + swz3(a0i));
      f32x4 y = *(const f32x4*)((const char*)AsL + swz3(a0i + 16));
      union { unsigned u[4]; short8 s; } r;
      r.u[0] = (__float_as_uint(x[0]) >> 16) | (__float_as_uint(x[1]) & 0xFFFF0000u);
      r.u[1] = (__float_as_uint(x[2]) >> 16) | (__float_as_uint(x[3]) & 0xFFFF0000u);
      r.u[2] = (__float_as_uint(y[0]) >> 16) | (__float_as_uint(y[1]) & 0xFFFF0000u);
      r.u[3] = (__float_as_uint(y[2]) >> 16) | (__float_as_uint(y[3]) & 0xFFFF0000u);
      af[m] = r.s;
    }
    #pragma unroll
    for (int n = 0; n < 4; ++n) {
      int a = (wc + n * 16 + llo) * 64 + lhi * 16;
      bfr[n] = *(const short8*)((const char*)BsL + swz2(a));
    }
    #pragma unroll
    for (int m = 0; m < 4; ++m)
      #pragma unroll
      for (int n = 0; n < 4; ++n)
        acc[m][n] = __builtin_amdgcn_mfma_f32_16x16x32_bf16(af[m], bfr[n], acc[m][n], 0, 0, 0);
    __syncthreads();
  }

  float* C = Cf + (size_t)z * SEQ * DIM;
  const float* Q = qres + (size_t)z * SEQ * DIM;
  #pragma unroll
  for (int m = 0; m < 4; ++m)
    #pragma unroll
    for (int r = 0; r < 4; ++r) {
      int rowg = brow + wr + m * 16 + lhi * 4 + r;
      #pragma unroll
      for (int n = 0; n < 4; ++n) {
        int colg = bcol + wc + n * 16 + llo;
        C[(size_t)rowg * DIM + colg] = acc[m][n][r] + Q[(size_t)rowg * DIM + colg];
      }
    }
}

// q,k,v f32 -> bf16 (RN). qb contiguous (out0 region); kb/vb into the upper
// 2048-ushort half of each weights-row slot (free until rowpass).
__global__ __launch_bounds__(256)
void prepack(const float* __restrict__ q, const float* __restrict__ k,
             const float* __restrict__ v, unsigned short* __restrict__ qb,
             unsigned short* __restrict__ wsl)
{
  const int NT = (BATCH * SEQ * DIM) / 4;
  for (int i = blockIdx.x * 256 + threadIdx.x; i < NT; i += 2048 * 256) {
    int e = i * 4;
    float4 qv = *(const float4*)(q + e);
    float4 kv = *(const float4*)(k + e);
    float4 vv = *(const float4*)(v + e);
    ushort4 qo; qo.x = f2bf(qv.x); qo.y = f2bf(qv.y); qo.z = f2bf(qv.z); qo.w = f2bf(qv.w);
    ushort4 ko; ko.x = f2bf(kv.x); ko.y = f2bf(kv.y); ko.z = f2bf(kv.z); ko.w = f2bf(kv.w);
    ushort4 vo; vo.x = f2bf(vv.x); vo.y = f2bf(vv.y); vo.z = f2bf(vv.z); vo.w = f2bf(vv.w);
    *(ushort4*)(qb + e) = qo;
    int r = e / DIM, c = e % DIM;
    size_t off = (size_t)r * 4096 + 2048 + c;
    *(ushort4*)(wsl + off) = ko;
    *(ushort4*)(wsl + off + DIM) = vo;
  }
}

// [R][C] f32 -> [C][R] bf16 (RN), 64x64 LDS tiles, batched via blockIdx.z
__global__ __launch_bounds__(256)
void transpose_f32_bf16(const float* __restrict__ src, unsigned short* __restrict__ dst,
                        int R, int C)
{
  __shared__ unsigned short T[64][65];
  const float* s = src + (size_t)blockIdx.z * R * C;
  unsigned short* d = dst + (size_t)blockIdx.z * R * C;
  int r0 = blockIdx.y * 64, c0 = blockIdx.x * 64;
  int tr = threadIdx.x >> 6, tc = threadIdx.x & 63;
  #pragma unroll
  for (int j = 0; j < 16; ++j) {
    int row = j * 4 + tr;
    T[row][tc] = f2bf(s[(size_t)(r0 + row) * C + c0 + tc]);
  }
  __syncthreads();
  #pragma unroll
  for (int j = 0; j < 16; ++j) {
    int row = j * 4 + tr;
    d[(size_t)(c0 + row) * R + r0 + tc] = T[tc][row];
  }
}

__global__ void g_combine(const float* __restrict__ pg, const float* __restrict__ b2,
                          float* __restrict__ g)
{
  int i = blockIdx.x * 256 + threadIdx.x;
  g[i] = b2[0] + pg[i] + pg[16384 + i] + pg[2 * 16384 + i] + pg[3 * 16384 + i];
}

// Column (query-axis) sum of exp — max-free (|score| <= ~4, no overflow risk)
__global__ __launch_bounds__(256)
void colstat_part(const unsigned short* __restrict__ sc, float* __restrict__ pl)
{
  const int gc = blockIdx.x * 256 + threadIdx.x;
  const int b = gc >> 11, c = gc & 2047;
  const unsigned short* p = sc + (size_t)b * SEQ * 4096 + c;
  const int q0 = blockIdx.y * 128;
  float l = 0.f;
  #pragma unroll 4
  for (int qq = q0; qq < q0 + 128; ++qq) l += __expf(bf2f(p[(size_t)qq * 4096]));
  pl[blockIdx.y * 16384 + gc] = l;
}

__global__ void colstat_comb(const float* __restrict__ pl, float* __restrict__ lcol)
{
  int gc = blockIdx.x * 256 + threadIdx.x;
  float l = 0.f;
  #pragma unroll
  for (int ch = 0; ch < 16; ++ch) l += pl[ch * 16384 + gc];
  lcol[gc] = l;
}

// Row pass: s = exp(x)/lcol; t = (s*(1-g) + g/S)/sqrt(768); row softmax.
// In-place bf16->f32; optional bf16 weights copy (FAST tier).
template<bool FAST>
__global__ __launch_bounds__(256)
void rowpass(float* __restrict__ w, const float* __restrict__ lcol,
             const float* __restrict__ gg, unsigned short* __restrict__ wb)
{
  const size_t row = blockIdx.x;
  const int b = (int)(row >> 11);
  const unsigned short* p = (const unsigned short*)w + row * 4096;
  float* wrow = w + row * 2048;
  const int c0 = threadIdx.x * 8;
  const float* lc = lcol + (b << 11);
  const float* gb = gg + (b << 11);

  unsigned short xs[8];
  *(ushort4*)&xs[0] = *(const ushort4*)(p + c0);
  *(ushort4*)&xs[4] = *(const ushort4*)(p + c0 + 4);
  float ls[8], gs[8];
  *(float4*)&ls[0] = *(const float4*)(lc + c0);
  *(float4*)&ls[4] = *(const float4*)(lc + c0 + 4);
  *(float4*)&gs[0] = *(const float4*)(gb + c0);
  *(float4*)&gs[4] = *(const float4*)(gb + c0 + 4);

  float e[8];
  float psum = 0.f;
  #pragma unroll
  for (int j = 0; j < 8; ++j) {
    float s = __expf(bf2f(xs[j])) / ls[j];
    float t = (s * (1.f - gs[j]) + gs[j] * (1.f / 2048.f)) * 0.03608439182435161f;
    float ev = __expf(t);
    e[j] = ev;
    psum += ev;
  }
  #pragma unroll
  for (int off = 1; off < 64; off <<= 1) psum += __shfl_xor(psum, off);
  __shared__ float red[4];
  if ((threadIdx.x & 63) == 0) red[threadIdx.x >> 6] = psum;
  __syncthreads();
  float inv = 1.f / (red[0] + red[1] + red[2] + red[3]);
  float4 o0, o1;
  o0.x = e[0] * inv; o0.y = e[1] * inv; o0.z = e[2] * inv; o0.w = e[3] * inv;
  o1.x = e[4] * inv; o1.y = e[5] * inv; o1.z = e[6] * inv; o1.w = e[7] * inv;
  *(float4*)(wrow + c0) = o0;
  *(float4*)(wrow + c0 + 4) = o1;
  if constexpr (FAST) {
    ushort4 b0, b1v;
    b0.x = f2bf(o0.x); b0.y = f2bf(o0.y); b0.z = f2bf(o0.z); b0.w = f2bf(o0.w);
    b1v.x = f2bf(o1.x); b1v.y = f2bf(o1.y); b1v.z = f2bf(o1.z); b1v.w = f2bf(o1.w);
    *(ushort4*)(wb + row * 2048 + c0) = b0;
    *(ushort4*)(wb + row * 2048 + c0 + 4) = b1v;
  }
}

extern "C" void kernel_launch(void* const* d_in, const int* in_sizes, int n_in,
                              void* d_out, int out_size, void* d_ws, size_t ws_size,
                              hipStream_t stream)
{
  (void)in_sizes; (void)n_in; (void)out_size;
  const float* q  = (const float*)d_in[0];
  const float* k  = (const float*)d_in[1];
  const float* v  = (const float*)d_in[2];
  const float* W1 = (const float*)d_in[3];
  const float* b1 = (const float*)d_in[4];
  const float* W2 = (const float*)d_in[5];
  const float* b2 = (const float*)d_in[6];

  float* out0 = (float*)d_out;                       // [B,S,D] f32 (holds qb until VAR2)
  float* wbuf = out0 + (size_t)BATCH * SEQ * DIM;    // [B,S,S] f32 weights slots
  unsigned short* wsl = (unsigned short*)wbuf;       // slot view (lower: scores, upper: kb/vb)
  unsigned short* qb  = (unsigned short*)out0;

  float* g    = (float*)d_ws;                        // 16384
  float* lcol = g + 16384;                           // 16384
  float* pg   = lcol + 16384;                        // 65536
  float* pl   = pg + 65536;                          // 262144
  unsigned short* W1T = (unsigned short*)(pl + 262144);            // 393216 ushorts
  unsigned short* vT  = (unsigned short*)((char*)d_ws + 2228224);  // 12.58M ushorts
  unsigned short* wb  = vT + (size_t)12582912;                     // 33.55M ushorts
  const bool fast = ws_size >= 94502912ull;

  prepack<<<2048, 256, 0, stream>>>(q, k, v, qb, wsl);
  transpose_f32_bf16<<<dim3(8, 12, 1), 256, 0, stream>>>(W1, W1T, 768, 512);
  if (fast)
    transpose_f32_bf16<<<dim3(12, 32, 8), 256, 0, stream>>>(v, vT, 2048, 768);

  gemm_db<0><<<512, 256, 0, stream>>>(wsl + 2816, W1T, b1, W2, pg, nullptr, nullptr);
  g_combine<<<64, 256, 0, stream>>>(pg, b2, g);

  gemm_db<1><<<2048, 256, 0, stream>>>(qb, wsl + 2048, nullptr, nullptr, nullptr, nullptr, wbuf);

  colstat_part<<<dim3(64, 16), 256, 0, stream>>>(wsl, pl);
  colstat_comb<<<64, 256, 0, stream>>>(pl, lcol);

  if (fast) {
    rowpass<true><<<16384, 256, 0, stream>>>(wbuf, lcol, g, wb);
    gemm_db<2><<<768, 256, 0, stream>>>(wb, vT, nullptr, nullptr, nullptr, q, out0);
  } else {
    rowpass<false><<<16384, 256, 0, stream>>>(wbuf, lcol, g, nullptr);
    gemm_slow<<<dim3(6, 16, 8), 256, 0, stream>>>(wbuf, v, q, out0);
  }
}

// Round 5
// 274.940 us; speedup vs baseline: 1.6525x; 1.1320x over previous
//
#include <hip/hip_runtime.h>

#define BATCH 8
#define SEQ   2048
#define DIM   768
#define HID   512

typedef __attribute__((ext_vector_type(8))) short  short8;
typedef __attribute__((ext_vector_type(4))) float  f32x4;

#define BAR()   asm volatile("s_barrier" ::: "memory")
#define WAITL0() asm volatile("s_waitcnt lgkmcnt(0)" ::: "memory")
#define VMC(n)  asm volatile("s_waitcnt vmcnt(" #n ")" ::: "memory")

__device__ __forceinline__ unsigned short f2bf(float f) {
  union { float f; unsigned u; } x; x.f = f;
  return (unsigned short)((x.u + 0x7FFFu + ((x.u >> 16) & 1u)) >> 16);
}
__device__ __forceinline__ float bf2f(unsigned short u) {
  union { unsigned u; float f; } x; x.u = ((unsigned)u) << 16;
  return x.f;
}
__device__ __forceinline__ void gll16(const void* g, void* l) {
  __builtin_amdgcn_global_load_lds(
      (const __attribute__((address_space(1))) void*)g,
      (__attribute__((address_space(3))) void*)l, 16, 0, 0);
}
// XOR swizzles (involutions; keep bits 0-3 so 16B chunks stay contiguous)
__device__ __forceinline__ int swz2(int o) { return o ^ (((o >> 8) & 7) << 4); }  // 64B rows
__device__ __forceinline__ int swz3(int o) { return o ^ (((o >> 7) & 7) << 4); }  // 128B rows

// ---------------------------------------------------------------------------
// 8-phase 256x256 BK=64 bf16 GEMM, 8 waves (2M x 4N), 512 threads, LDS 128KiB.
// Phase = (M-half h, N-half nh) Gray order; 16 MFMA/phase; 1 half-tile staged
// per phase via global_load_lds(16B, linear dest + inverse-swizzled source);
// counted vmcnt(4) gates at P4/P8 only. K-chunk order identical to the 2-phase
// kernel -> bit-identical results.
// VAR 1: scores  A=qb[z] pitch 1536B, B=kb slots pitch 8192B, K=768
//                C -> bf16 at C16[R*4096+col], *1/sqrt(2048)
// VAR 2: PV      A=wb[z] pitch 4096B, B=vT[z] pitch 4096B, K=2048
//                C -> f32 out + q residual
// ---------------------------------------------------------------------------
template<int VAR>
__global__ __launch_bounds__(512, 2)
void gemm8(const unsigned short* __restrict__ Ap, const unsigned short* __restrict__ Bp,
           const float* __restrict__ qres, float* __restrict__ Cf)
{
  constexpr int K     = (VAR == 1) ? DIM : SEQ;
  constexpr int NT    = K / 64;
  constexpr int NITER = NT / 2;
  constexpr int APB   = (VAR == 1) ? DIM * 2 : SEQ * 2;   // A row pitch (bytes)
  constexpr int BPB   = (VAR == 1) ? 8192    : SEQ * 2;   // B row pitch (bytes)
  constexpr int GX    = (VAR == 1) ? 8 : 3;
  constexpr int GY    = 8;
  constexpr int NWG   = GX * GY * BATCH;

  __shared__ __align__(16) unsigned char LDS[131072];     // A: 2x32K @0, B: 2x32K @64K

  int wg = ((blockIdx.x & 7) * (NWG >> 3)) + ((int)blockIdx.x >> 3);
  const int z  = wg / (GX * GY);
  const int r2 = wg % (GX * GY);
  const int by = r2 / GX;
  const int bx = r2 % GX;
  const int brow = by * 256, bcol = bx * 256;

  const int tid  = threadIdx.x;
  const int lane = tid & 63, wid = tid >> 6;
  const int wm   = wid >> 2, wn = wid & 3;
  const int lhi  = lane >> 4, llo = lane & 15;

  const char* Abase;
  const char* Bbase;
  if constexpr (VAR == 1) {
    Abase = (const char*)(Ap + (size_t)z * SEQ * DIM) + (size_t)brow * APB;
    Bbase = (const char*)(Bp + (size_t)z * SEQ * 4096 + 2048) + (size_t)bcol * BPB;
  } else {
    Abase = (const char*)(Ap + (size_t)z * SEQ * SEQ) + (size_t)brow * APB;
    Bbase = (const char*)(Bp + (size_t)z * (size_t)DIM * SEQ) + (size_t)bcol * BPB;
  }

  // per-thread staging constants: linear LDS dest o -> swizzled source (row,kb)
  int sr[2], sk[2];
  #pragma unroll
  for (int c = 0; c < 2; ++c) {
    int o = wid * 2048 + c * 1024 + lane * 16;
    int a = swz3(o);
    sr[c] = a >> 7; sk[c] = a & 127;
  }
  auto stA = [&](int buf, int hh, int t) {
    #pragma unroll
    for (int c = 0; c < 2; ++c)
      gll16(Abase + (size_t)(hh * 128 + sr[c]) * APB + t * 128 + sk[c],
            LDS + buf * 32768 + hh * 16384 + wid * 2048 + c * 1024);
  };
  auto stB = [&](int buf, int hh, int t) {
    #pragma unroll
    for (int c = 0; c < 2; ++c)
      gll16(Bbase + (size_t)(hh * 128 + sr[c]) * BPB + t * 128 + sk[c],
            LDS + 65536 + buf * 32768 + hh * 16384 + wid * 2048 + c * 1024);
  };

  f32x4 acc[8][4];
  #pragma unroll
  for (int m = 0; m < 8; ++m)
    #pragma unroll
    for (int n = 0; n < 4; ++n)
      acc[m][n] = (f32x4)(0.0f);

  // prologue: tile0 fully (buf0) + tile1 B (buf1); A of tile1 staged at P1,P2
  stA(0, 0, 0); stA(0, 1, 0); stB(0, 0, 0); stB(0, 1, 0);
  stB(1, 0, 1); stB(1, 1, 1);
  VMC(4);               // tile0's 8 gll forced complete; tile1's B may fly
  BAR();

  auto ITER = [&](int i, bool last) {
    #pragma unroll
    for (int kk = 0; kk < 2; ++kk) {
      const int buf = kk;
      short8 aR[4][2], b0R[2][2], b1R[2][2];
      #pragma unroll
      for (int ph = 0; ph < 4; ++ph) {
        const int h  = ph >> 1;
        const int nh = (ph == 1 || ph == 2) ? 1 : 0;
        // ---- ds reads (pre-barrier; latency hidden under barrier wait)
        if (ph == 0 || ph == 2) {
          #pragma unroll
          for (int fm = 0; fm < 4; ++fm)
            #pragma unroll
            for (int kh = 0; kh < 2; ++kh) {
              int o = (wm * 128 + h * 64 + fm * 16 + llo) * 128 + kh * 64 + lhi * 16;
              aR[fm][kh] = *(const short8*)(LDS + buf * 32768 + swz3(o));
            }
        }
        if (ph == 0) {
          #pragma unroll
          for (int fn = 0; fn < 2; ++fn)
            #pragma unroll
            for (int kh = 0; kh < 2; ++kh) {
              int o = (wn * 64 + fn * 16 + llo) * 128 + kh * 64 + lhi * 16;
              b0R[fn][kh] = *(const short8*)(LDS + 65536 + buf * 32768 + swz3(o));
            }
        }
        if (ph == 1) {
          #pragma unroll
          for (int fn = 0; fn < 2; ++fn)
            #pragma unroll
            for (int kh = 0; kh < 2; ++kh) {
              int o = (wn * 64 + 32 + fn * 16 + llo) * 128 + kh * 64 + lhi * 16;
              b1R[fn][kh] = *(const short8*)(LDS + 65536 + buf * 32768 + swz3(o));
            }
        }
        // ---- stage one half-tile (map verified: >=1 barrier-pair after last read)
        const int P = kk * 4 + ph;
        if      (P == 0) stA(1, 0, 2 * i + 1);
        else if (P == 1) stA(1, 1, 2 * i + 1);
        else if (P == 2) { if (!last) stB(0, 0, 2 * i + 2); }
        else if (P == 3) { if (!last) stB(0, 1, 2 * i + 2); }
        else if (P == 4) { if (!last) stA(0, 0, 2 * i + 2); }
        else if (P == 5) { if (!last) stA(0, 1, 2 * i + 2); }
        else if (P == 6) { if (!last) stB(1, 0, 2 * i + 3); }
        else if (P == 7) { if (!last) stB(1, 1, 2 * i + 3); }
        // ---- gates: once per K-tile, counted (never 0 except final)
        if (P == 3) { if (last) { VMC(0); } else { VMC(4); } }
        if (P == 7) { if (!last) { VMC(4); } }
        BAR();
        WAITL0();
        __builtin_amdgcn_sched_barrier(0);
        __builtin_amdgcn_s_setprio(1);
        #pragma unroll
        for (int kh = 0; kh < 2; ++kh)
          #pragma unroll
          for (int fm = 0; fm < 4; ++fm)
            #pragma unroll
            for (int fn = 0; fn < 2; ++fn)
              acc[h * 4 + fm][nh * 2 + fn] = __builtin_amdgcn_mfma_f32_16x16x32_bf16(
                  aR[fm][kh], nh ? b1R[fn][kh] : b0R[fn][kh],
                  acc[h * 4 + fm][nh * 2 + fn], 0, 0, 0);
        __builtin_amdgcn_s_setprio(0);
        BAR();
      }
    }
  };

  for (int i = 0; i < NITER - 1; ++i) ITER(i, false);
  ITER(NITER - 1, true);

  // ---- epilogue (C/D: col = lane&15, row = (lane>>4)*4 + r)
  if constexpr (VAR == 1) {
    const float rs = 0.02209708691207961f;  // 1/sqrt(2048)
    unsigned short* C16 = reinterpret_cast<unsigned short*>(Cf);
    #pragma unroll
    for (int FM = 0; FM < 8; ++FM)
      #pragma unroll
      for (int r = 0; r < 4; ++r) {
        size_t R = (size_t)z * SEQ + (brow + wm * 128 + FM * 16 + lhi * 4 + r);
        #pragma unroll
        for (int FN = 0; FN < 4; ++FN) {
          int col = bcol + wn * 64 + FN * 16 + llo;
          C16[R * 4096 + col] = f2bf(acc[FM][FN][r] * rs);
        }
      }
  }
  if constexpr (VAR == 2) {
    float* C = Cf + (size_t)z * SEQ * DIM;
    const float* Q = qres + (size_t)z * SEQ * DIM;
    #pragma unroll
    for (int FM = 0; FM < 8; ++FM)
      #pragma unroll
      for (int r = 0; r < 4; ++r) {
        int rowg = brow + wm * 128 + FM * 16 + lhi * 4 + r;
        #pragma unroll
        for (int FN = 0; FN < 4; ++FN) {
          int colg = bcol + wn * 64 + FN * 16 + llo;
          C[(size_t)rowg * DIM + colg] = acc[FM][FN][r] + Q[(size_t)rowg * DIM + colg];
        }
      }
  }
}

// ---------------------------------------------------------------------------
// 2-phase 128x128 GEMM, kept for the gate (VAR 0) — proven in round 4.
// ---------------------------------------------------------------------------
__global__ __launch_bounds__(256)
void gemm_gate(const unsigned short* __restrict__ Ab, const unsigned short* __restrict__ Bb,
               const float* __restrict__ bias, const float* __restrict__ W2,
               float* __restrict__ pg)
{
  constexpr int K = DIM, NT = K / 32, APITCH = 4096, BPITCH = DIM;
  constexpr int GX = 4, NWG = 512;

  __shared__ __align__(16) unsigned short AsL[2 * 128 * 32];
  __shared__ __align__(16) unsigned short BsL[2 * 128 * 32];
  __shared__ float gred[128][2];

  int wg = blockIdx.x;
  wg = (wg & 7) * (NWG >> 3) + (wg >> 3);
  const int bx = wg % GX;
  const int by = wg / GX;

  const int tid  = threadIdx.x;
  const int brow = by * 128;
  const int bcol = bx * 128;
  const int lane = tid & 63;
  const int wid  = tid >> 6;
  const int wr   = (wid >> 1) * 64;
  const int wc   = (wid & 1) * 64;
  const int lhi  = lane >> 4;
  const int llo  = lane & 15;

  const unsigned short* Asrc = Ab + (size_t)brow * APITCH;
  const unsigned short* Bsrc = Bb + (size_t)bcol * BPITCH;

  f32x4 acc[4][4];
  #pragma unroll
  for (int m = 0; m < 4; ++m)
    #pragma unroll
    for (int n = 0; n < 4; ++n)
      acc[m][n] = (f32x4)(0.0f);

  auto stage = [&](int buf, int k0) {
    #pragma unroll
    for (int i = 0; i < 2; ++i) {
      int ob = wid * 2048 + i * 1024;
      int a  = swz2(ob + lane * 16);
      gll16((const char*)Asrc + (size_t)(a >> 6) * (APITCH * 2) + (size_t)k0 * 2 + (a & 63),
            (char*)AsL + buf * 8192 + ob);
    }
    #pragma unroll
    for (int i = 0; i < 2; ++i) {
      int ob = wid * 2048 + i * 1024;
      int a  = swz2(ob + lane * 16);
      gll16((const char*)Bsrc + (size_t)(a >> 6) * (BPITCH * 2) + (size_t)k0 * 2 + (a & 63),
            (char*)BsL + buf * 8192 + ob);
    }
  };

  stage(0, 0);
  for (int t = 0; t < NT; ++t) {
    if (t + 1 < NT) {
      stage((t + 1) & 1, (t + 1) * 32);
      VMC(4);
    } else {
      VMC(0);
    }
    BAR();
    __builtin_amdgcn_sched_barrier(0);

    const int bb = (t & 1) * 8192;
    short8 af[4], bfr[4];
    #pragma unroll
    for (int m = 0; m < 4; ++m) {
      int a = (wr + m * 16 + llo) * 64 + lhi * 16;
      af[m] = *(const short8*)((const char*)AsL + bb + swz2(a));
    }
    #pragma unroll
    for (int n = 0; n < 4; ++n) {
      int a = (wc + n * 16 + llo) * 64 + lhi * 16;
      bfr[n] = *(const short8*)((const char*)BsL + bb + swz2(a));
    }
    #pragma unroll
    for (int m = 0; m < 4; ++m)
      #pragma unroll
      for (int n = 0; n < 4; ++n)
        acc[m][n] = __builtin_amdgcn_mfma_f32_16x16x32_bf16(af[m], bfr[n], acc[m][n], 0, 0, 0);

    __builtin_amdgcn_sched_barrier(0);
    BAR();
    __builtin_amdgcn_sched_barrier(0);
  }

  #pragma unroll
  for (int m = 0; m < 4; ++m) {
    #pragma unroll
    for (int r = 0; r < 4; ++r) {
      int lrow = wr + m * 16 + lhi * 4 + r;
      float part = 0.f;
      #pragma unroll
      for (int n = 0; n < 4; ++n) {
        int colg = bcol + wc + n * 16 + llo;
        float t = tanhf(acc[m][n][r] + bias[colg]);
        part += t * W2[colg];
      }
      part += __shfl_xor(part, 1);
      part += __shfl_xor(part, 2);
      part += __shfl_xor(part, 4);
      part += __shfl_xor(part, 8);
      if (llo == 0) gred[lrow][wid & 1] = part;
    }
  }
  __syncthreads();
  if (tid < 128)
    pg[(size_t)bx * 16384 + brow + tid] = gred[tid][0] + gred[tid][1];
}

// ---------------------------------------------------------------------------
// Fallback PV GEMM (f32 weights + f32 v), single-buffer — only if ws too small.
// ---------------------------------------------------------------------------
__global__ __launch_bounds__(256)
void gemm_slow(const float* __restrict__ Wf, const float* __restrict__ Vf,
               const float* __restrict__ qres, float* __restrict__ Cf)
{
  __shared__ __align__(16) unsigned short AsL[128 * 64];
  __shared__ __align__(16) unsigned short BsL[128 * 32];

  const int tid  = threadIdx.x;
  const int z    = blockIdx.z;
  const int brow = blockIdx.y * 128;
  const int bcol = blockIdx.x * 128;
  const int lane = tid & 63;
  const int wid  = tid >> 6;
  const int wr   = (wid >> 1) * 64;
  const int wc   = (wid & 1) * 64;
  const int lhi  = lane >> 4;
  const int llo  = lane & 15;

  const float* AsrcF = Wf + (size_t)z * SEQ * SEQ + (size_t)brow * SEQ;
  const float* BsrcF = Vf + (size_t)z * SEQ * DIM;

  f32x4 acc[4][4];
  #pragma unroll
  for (int m = 0; m < 4; ++m)
    #pragma unroll
    for (int n = 0; n < 4; ++n)
      acc[m][n] = (f32x4)(0.0f);

  for (int k0 = 0; k0 < SEQ; k0 += 32) {
    #pragma unroll
    for (int i = 0; i < 4; ++i) {
      int ob = wid * 4096 + i * 1024;
      int a  = swz3(ob + lane * 16);
      gll16((const char*)AsrcF + (size_t)(a >> 7) * (SEQ * 4) + (size_t)k0 * 4 + (a & 127),
            (char*)AsL + ob);
    }
    {
      int n4 = (tid & 31) << 2;
      int kb = (tid >> 5) << 2;
      float4 r0 = *(const float4*)(BsrcF + (size_t)(k0 + kb + 0) * DIM + bcol + n4);
      float4 r1 = *(const float4*)(BsrcF + (size_t)(k0 + kb + 1) * DIM + bcol + n4);
      float4 r2 = *(const float4*)(BsrcF + (size_t)(k0 + kb + 2) * DIM + bcol + n4);
      float4 r3 = *(const float4*)(BsrcF + (size_t)(k0 + kb + 3) * DIM + bcol + n4);
      float a0[4] = {r0.x, r0.y, r0.z, r0.w};
      float a1[4] = {r1.x, r1.y, r1.z, r1.w};
      float a2[4] = {r2.x, r2.y, r2.z, r2.w};
      float a3[4] = {r3.x, r3.y, r3.z, r3.w};
      #pragma unroll
      for (int jj = 0; jj < 4; ++jj) {
        unsigned lo = (__float_as_uint(a0[jj]) >> 16) | (__float_as_uint(a1[jj]) & 0xFFFF0000u);
        unsigned hi = (__float_as_uint(a2[jj]) >> 16) | (__float_as_uint(a3[jj]) & 0xFFFF0000u);
        int ol = (n4 + jj) * 64 + kb * 2;
        *(uint2*)((char*)BsL + swz2(ol)) = make_uint2(lo, hi);
      }
    }
    __syncthreads();

    short8 af[4], bfr[4];
    #pragma unroll
    for (int m = 0; m < 4; ++m) {
      int row = wr + m * 16 + llo;
      int a0i = row * 128 + lhi * 32;
      f32x4 x = *(const f32x4*)((const char*)AsL + swz3(a0i));
      f32x4 y = *(const f32x4*)((const char*)AsL + swz3(a0i + 16));
      union { unsigned u[4]; short8 s; } r;
      r.u[0] = (__float_as_uint(x[0]) >> 16) | (__float_as_uint(x[1]) & 0xFFFF0000u);
      r.u[1] = (__float_as_uint(x[2]) >> 16) | (__float_as_uint(x[3]) & 0xFFFF0000u);
      r.u[2] = (__float_as_uint(y[0]) >> 16) | (__float_as_uint(y[1]) & 0xFFFF0000u);
      r.u[3] = (__float_as_uint(y[2]) >> 16) | (__float_as_uint(y[3]) & 0xFFFF0000u);
      af[m] = r.s;
    }
    #pragma unroll
    for (int n = 0; n < 4; ++n) {
      int a = (wc + n * 16 + llo) * 64 + lhi * 16;
      bfr[n] = *(const short8*)((const char*)BsL + swz2(a));
    }
    #pragma unroll
    for (int m = 0; m < 4; ++m)
      #pragma unroll
      for (int n = 0; n < 4; ++n)
        acc[m][n] = __builtin_amdgcn_mfma_f32_16x16x32_bf16(af[m], bfr[n], acc[m][n], 0, 0, 0);
    __syncthreads();
  }

  float* C = Cf + (size_t)z * SEQ * DIM;
  const float* Q = qres + (size_t)z * SEQ * DIM;
  #pragma unroll
  for (int m = 0; m < 4; ++m)
    #pragma unroll
    for (int r = 0; r < 4; ++r) {
      int rowg = brow + wr + m * 16 + lhi * 4 + r;
      #pragma unroll
      for (int n = 0; n < 4; ++n) {
        int colg = bcol + wc + n * 16 + llo;
        C[(size_t)rowg * DIM + colg] = acc[m][n][r] + Q[(size_t)rowg * DIM + colg];
      }
    }
}

// q,k,v f32 -> bf16 (RN). qb contiguous (out0 region); kb/vb into the upper
// 2048-ushort half of each weights-row slot (free until rowpass).
__global__ __launch_bounds__(256)
void prepack(const float* __restrict__ q, const float* __restrict__ k,
             const float* __restrict__ v, unsigned short* __restrict__ qb,
             unsigned short* __restrict__ wsl)
{
  const int NT = (BATCH * SEQ * DIM) / 4;
  for (int i = blockIdx.x * 256 + threadIdx.x; i < NT; i += 2048 * 256) {
    int e = i * 4;
    float4 qv = *(const float4*)(q + e);
    float4 kv = *(const float4*)(k + e);
    float4 vv = *(const float4*)(v + e);
    ushort4 qo; qo.x = f2bf(qv.x); qo.y = f2bf(qv.y); qo.z = f2bf(qv.z); qo.w = f2bf(qv.w);
    ushort4 ko; ko.x = f2bf(kv.x); ko.y = f2bf(kv.y); ko.z = f2bf(kv.z); ko.w = f2bf(kv.w);
    ushort4 vo; vo.x = f2bf(vv.x); vo.y = f2bf(vv.y); vo.z = f2bf(vv.z); vo.w = f2bf(vv.w);
    *(ushort4*)(qb + e) = qo;
    int r = e / DIM, c = e % DIM;
    size_t off = (size_t)r * 4096 + 2048 + c;
    *(ushort4*)(wsl + off) = ko;
    *(ushort4*)(wsl + off + DIM) = vo;
  }
}

// [R][C] f32 -> [C][R] bf16 (RN), 64x64 LDS tiles, batched via blockIdx.z
__global__ __launch_bounds__(256)
void transpose_f32_bf16(const float* __restrict__ src, unsigned short* __restrict__ dst,
                        int R, int C)
{
  __shared__ unsigned short T[64][65];
  const float* s = src + (size_t)blockIdx.z * R * C;
  unsigned short* d = dst + (size_t)blockIdx.z * R * C;
  int r0 = blockIdx.y * 64, c0 = blockIdx.x * 64;
  int tr = threadIdx.x >> 6, tc = threadIdx.x & 63;
  #pragma unroll
  for (int j = 0; j < 16; ++j) {
    int row = j * 4 + tr;
    T[row][tc] = f2bf(s[(size_t)(r0 + row) * C + c0 + tc]);
  }
  __syncthreads();
  #pragma unroll
  for (int j = 0; j < 16; ++j) {
    int row = j * 4 + tr;
    d[(size_t)(c0 + row) * R + r0 + tc] = T[tc][row];
  }
}

__global__ void g_combine(const float* __restrict__ pg, const float* __restrict__ b2,
                          float* __restrict__ g)
{
  int i = blockIdx.x * 256 + threadIdx.x;
  g[i] = b2[0] + pg[i] + pg[16384 + i] + pg[2 * 16384 + i] + pg[3 * 16384 + i];
}

// Column (query-axis) sum of exp — max-free (|score| <= ~4, no overflow risk)
__global__ __launch_bounds__(256)
void colstat_part(const unsigned short* __restrict__ sc, float* __restrict__ pl)
{
  const int gc = blockIdx.x * 256 + threadIdx.x;
  const int b = gc >> 11, c = gc & 2047;
  const unsigned short* p = sc + (size_t)b * SEQ * 4096 + c;
  const int q0 = blockIdx.y * 128;
  float l = 0.f;
  #pragma unroll 4
  for (int qq = q0; qq < q0 + 128; ++qq) l += __expf(bf2f(p[(size_t)qq * 4096]));
  pl[blockIdx.y * 16384 + gc] = l;
}

__global__ void colstat_comb(const float* __restrict__ pl, float* __restrict__ lcol)
{
  int gc = blockIdx.x * 256 + threadIdx.x;
  float l = 0.f;
  #pragma unroll
  for (int ch = 0; ch < 16; ++ch) l += pl[ch * 16384 + gc];
  lcol[gc] = l;
}

// Row pass: s = exp(x)/lcol; t = (s*(1-g) + g/S)/sqrt(768); row softmax.
// In-place bf16->f32; optional bf16 weights copy (FAST tier).
template<bool FAST>
__global__ __launch_bounds__(256)
void rowpass(float* __restrict__ w, const float* __restrict__ lcol,
             const float* __restrict__ gg, unsigned short* __restrict__ wb)
{
  const size_t row = blockIdx.x;
  const int b = (int)(row >> 11);
  const unsigned short* p = (const unsigned short*)w + row * 4096;
  float* wrow = w + row * 2048;
  const int c0 = threadIdx.x * 8;
  const float* lc = lcol + (b << 11);
  const float* gb = gg + (b << 11);

  unsigned short xs[8];
  *(ushort4*)&xs[0] = *(const ushort4*)(p + c0);
  *(ushort4*)&xs[4] = *(const ushort4*)(p + c0 + 4);
  float ls[8], gs[8];
  *(float4*)&ls[0] = *(const float4*)(lc + c0);
  *(float4*)&ls[4] = *(const float4*)(lc + c0 + 4);
  *(float4*)&gs[0] = *(const float4*)(gb + c0);
  *(float4*)&gs[4] = *(const float4*)(gb + c0 + 4);

  float e[8];
  float psum = 0.f;
  #pragma unroll
  for (int j = 0; j < 8; ++j) {
    float s = __expf(bf2f(xs[j])) / ls[j];
    float t = (s * (1.f - gs[j]) + gs[j] * (1.f / 2048.f)) * 0.03608439182435161f;
    float ev = __expf(t);
    e[j] = ev;
    psum += ev;
  }
  #pragma unroll
  for (int off = 1; off < 64; off <<= 1) psum += __shfl_xor(psum, off);
  __shared__ float red[4];
  if ((threadIdx.x & 63) == 0) red[threadIdx.x >> 6] = psum;
  __syncthreads();
  float inv = 1.f / (red[0] + red[1] + red[2] + red[3]);
  float4 o0, o1;
  o0.x = e[0] * inv; o0.y = e[1] * inv; o0.z = e[2] * inv; o0.w = e[3] * inv;
  o1.x = e[4] * inv; o1.y = e[5] * inv; o1.z = e[6] * inv; o1.w = e[7] * inv;
  *(float4*)(wrow + c0) = o0;
  *(float4*)(wrow + c0 + 4) = o1;
  if constexpr (FAST) {
    ushort4 b0, b1v;
    b0.x = f2bf(o0.x); b0.y = f2bf(o0.y); b0.z = f2bf(o0.z); b0.w = f2bf(o0.w);
    b1v.x = f2bf(o1.x); b1v.y = f2bf(o1.y); b1v.z = f2bf(o1.z); b1v.w = f2bf(o1.w);
    *(ushort4*)(wb + row * 2048 + c0) = b0;
    *(ushort4*)(wb + row * 2048 + c0 + 4) = b1v;
  }
}

extern "C" void kernel_launch(void* const* d_in, const int* in_sizes, int n_in,
                              void* d_out, int out_size, void* d_ws, size_t ws_size,
                              hipStream_t stream)
{
  (void)in_sizes; (void)n_in; (void)out_size;
  const float* q  = (const float*)d_in[0];
  const float* k  = (const float*)d_in[1];
  const float* v  = (const float*)d_in[2];
  const float* W1 = (const float*)d_in[3];
  const float* b1 = (const float*)d_in[4];
  const float* W2 = (const float*)d_in[5];
  const float* b2 = (const float*)d_in[6];

  float* out0 = (float*)d_out;                       // [B,S,D] f32 (holds qb until PV)
  float* wbuf = out0 + (size_t)BATCH * SEQ * DIM;    // [B,S,S] f32 weights slots
  unsigned short* wsl = (unsigned short*)wbuf;       // slot view (lower: scores, upper: kb/vb)
  unsigned short* qb  = (unsigned short*)out0;

  float* g    = (float*)d_ws;                        // 16384
  float* lcol = g + 16384;                           // 16384
  float* pg   = lcol + 16384;                        // 65536
  float* pl   = pg + 65536;                          // 262144
  unsigned short* W1T = (unsigned short*)(pl + 262144);            // 393216 ushorts
  unsigned short* vT  = (unsigned short*)((char*)d_ws + 2228224);  // 12.58M ushorts
  unsigned short* wb  = vT + (size_t)12582912;                     // 33.55M ushorts
  const bool fast = ws_size >= 94502912ull;

  prepack<<<2048, 256, 0, stream>>>(q, k, v, qb, wsl);
  transpose_f32_bf16<<<dim3(8, 12, 1), 256, 0, stream>>>(W1, W1T, 768, 512);
  if (fast)
    transpose_f32_bf16<<<dim3(12, 32, 8), 256, 0, stream>>>(v, vT, 2048, 768);

  gemm_gate<<<512, 256, 0, stream>>>(wsl + 2816, W1T, b1, W2, pg);
  g_combine<<<64, 256, 0, stream>>>(pg, b2, g);

  // scores: 8-phase 256^2 (A=qb, B=kb slots) -> bf16 packed into weights rows
  gemm8<1><<<512, 512, 0, stream>>>(qb, wsl, nullptr, wbuf);

  colstat_part<<<dim3(64, 16), 256, 0, stream>>>(wsl, pl);
  colstat_comb<<<64, 256, 0, stream>>>(pl, lcol);

  if (fast) {
    rowpass<true><<<16384, 256, 0, stream>>>(wbuf, lcol, g, wb);
    gemm8<2><<<192, 512, 0, stream>>>(wb, vT, q, out0);
  } else {
    rowpass<false><<<16384, 256, 0, stream>>>(wbuf, lcol, g, nullptr);
    gemm_slow<<<dim3(6, 16, 8), 256, 0, stream>>>(wbuf, v, q, out0);
  }
}

// Round 6
// 260.907 us; speedup vs baseline: 1.7414x; 1.0538x over previous
//
#include <hip/hip_runtime.h>

#define BATCH 8
#define SEQ   2048
#define DIM   768
#define HID   512

typedef __attribute__((ext_vector_type(8))) short  short8;
typedef __attribute__((ext_vector_type(4))) float  f32x4;

#define BAR()    asm volatile("s_barrier" ::: "memory")
#define WAITL0() asm volatile("s_waitcnt lgkmcnt(0)" ::: "memory")
#define VMC(n)   asm volatile("s_waitcnt vmcnt(" #n ")" ::: "memory")

__device__ __forceinline__ unsigned short f2bf(float f) {
  union { float f; unsigned u; } x; x.f = f;
  return (unsigned short)((x.u + 0x7FFFu + ((x.u >> 16) & 1u)) >> 16);
}
__device__ __forceinline__ float bf2f(unsigned short u) {
  union { unsigned u; float f; } x; x.u = ((unsigned)u) << 16;
  return x.f;
}
__device__ __forceinline__ void gll16(const void* g, void* l) {
  __builtin_amdgcn_global_load_lds(
      (const __attribute__((address_space(1))) void*)g,
      (__attribute__((address_space(3))) void*)l, 16, 0, 0);
}
// XOR swizzles (involutions; keep bits 0-3 so 16B chunks stay contiguous)
__device__ __forceinline__ int swz2(int o) { return o ^ (((o >> 8) & 7) << 4); }  // 64B rows
__device__ __forceinline__ int swz3(int o) { return o ^ (((o >> 7) & 7) << 4); }  // 128B rows

// ---------------------------------------------------------------------------
// 8-phase 256x256 BK=64 bf16 GEMM, 8 waves (2M x 4N), 512 threads, LDS 128KiB.
// Counted vmcnt(4) gates at P4/P8 only; st-swizzled LDS via pre-swizzled
// global_load_lds source. K-chunk order fixed -> deterministic results.
// VAR 0: gate    A=vb slots pitch 8192B, B=W1T pitch 1536B, K=768, grid 128
//                epilogue: tanh(acc+b1)·W2 row-reduce -> pg[2][16384]
// VAR 1: scores  A=qb pitch 1536B, B=kb slots pitch 8192B, K=768, grid 512
//                epilogue: bf16 C16[R*4096+col] (*1/sqrt2048) + per-block
//                column exp-sum partials -> pl[by][16384]
// VAR 2: PV      A=wb pitch 4096B, B=vT pitch 4096B, K=2048, grid 192
//                epilogue: f32 out + q residual
// ---------------------------------------------------------------------------
template<int VAR>
__global__ __launch_bounds__(512, 2)
void gemm8(const unsigned short* __restrict__ Ap, const unsigned short* __restrict__ Bp,
           const float* __restrict__ qres, float* __restrict__ Cf,
           const float* __restrict__ bias, const float* __restrict__ W2,
           float* __restrict__ pg, float* __restrict__ pl)
{
  constexpr int K     = (VAR == 2) ? SEQ : DIM;
  constexpr int NT    = K / 64;
  constexpr int NITER = NT / 2;
  constexpr int APB   = (VAR == 0) ? 8192 : (VAR == 1 ? 1536 : 4096);
  constexpr int BPB   = (VAR == 0) ? 1536 : (VAR == 1 ? 8192 : 4096);
  constexpr int GX    = (VAR == 0) ? 2 : (VAR == 1 ? 8 : 3);
  constexpr int GY    = (VAR == 0) ? 64 : 8;
  constexpr int NB    = (VAR == 0) ? 1 : BATCH;
  constexpr int NWG   = GX * GY * NB;

  __shared__ __align__(16) unsigned char LDS[131072];   // A: 2x32K @0, B: 2x32K @64K

  int wg = ((blockIdx.x & 7) * (NWG >> 3)) + ((int)blockIdx.x >> 3);
  const int z  = wg / (GX * GY);
  const int r2 = wg % (GX * GY);
  const int by = r2 / GX;
  const int bx = r2 % GX;
  const int brow = by * 256, bcol = bx * 256;

  const int tid  = threadIdx.x;
  const int lane = tid & 63, wid = tid >> 6;
  const int wm   = wid >> 2, wn = wid & 3;
  const int lhi  = lane >> 4, llo = lane & 15;

  const char* Abase;
  const char* Bbase;
  if constexpr (VAR == 0) {
    Abase = (const char*)Ap + (size_t)brow * APB;
    Bbase = (const char*)Bp + (size_t)bcol * BPB;
  } else if constexpr (VAR == 1) {
    Abase = (const char*)(Ap + (size_t)z * SEQ * DIM) + (size_t)brow * APB;
    Bbase = (const char*)(Bp + (size_t)z * SEQ * 4096 + 2048) + (size_t)bcol * BPB;
  } else {
    Abase = (const char*)(Ap + (size_t)z * SEQ * SEQ) + (size_t)brow * APB;
    Bbase = (const char*)(Bp + (size_t)z * (size_t)DIM * SEQ) + (size_t)bcol * BPB;
  }

  // staging: linear LDS dest o -> swizzled source (row,kb)
  int sr[2], sk[2];
  #pragma unroll
  for (int c = 0; c < 2; ++c) {
    int o = wid * 2048 + c * 1024 + lane * 16;
    int a = swz3(o);
    sr[c] = a >> 7; sk[c] = a & 127;
  }
  auto stA = [&](int buf, int hh, int t) {
    #pragma unroll
    for (int c = 0; c < 2; ++c)
      gll16(Abase + (size_t)(hh * 128 + sr[c]) * APB + t * 128 + sk[c],
            LDS + buf * 32768 + hh * 16384 + wid * 2048 + c * 1024);
  };
  auto stB = [&](int buf, int hh, int t) {
    #pragma unroll
    for (int c = 0; c < 2; ++c)
      gll16(Bbase + (size_t)(hh * 128 + sr[c]) * BPB + t * 128 + sk[c],
            LDS + 65536 + buf * 32768 + hh * 16384 + wid * 2048 + c * 1024);
  };

  f32x4 acc[8][4];
  #pragma unroll
  for (int m = 0; m < 8; ++m)
    #pragma unroll
    for (int n = 0; n < 4; ++n)
      acc[m][n] = (f32x4)(0.0f);

  // prologue: tile0 fully (buf0) + tile1 B (buf1); A of tile1 staged at P1,P2
  stA(0, 0, 0); stA(0, 1, 0); stB(0, 0, 0); stB(0, 1, 0);
  stB(1, 0, 1); stB(1, 1, 1);
  VMC(4);
  BAR();

  auto ITER = [&](int i, bool last) {
    #pragma unroll
    for (int kk = 0; kk < 2; ++kk) {
      const int buf = kk;
      short8 aR[4][2], b0R[2][2], b1R[2][2];
      #pragma unroll
      for (int ph = 0; ph < 4; ++ph) {
        const int h  = ph >> 1;
        const int nh = (ph == 1 || ph == 2) ? 1 : 0;
        if (ph == 0 || ph == 2) {
          #pragma unroll
          for (int fm = 0; fm < 4; ++fm)
            #pragma unroll
            for (int kh = 0; kh < 2; ++kh) {
              int o = (wm * 128 + h * 64 + fm * 16 + llo) * 128 + kh * 64 + lhi * 16;
              aR[fm][kh] = *(const short8*)(LDS + buf * 32768 + swz3(o));
            }
        }
        if (ph == 0) {
          #pragma unroll
          for (int fn = 0; fn < 2; ++fn)
            #pragma unroll
            for (int kh = 0; kh < 2; ++kh) {
              int o = (wn * 64 + fn * 16 + llo) * 128 + kh * 64 + lhi * 16;
              b0R[fn][kh] = *(const short8*)(LDS + 65536 + buf * 32768 + swz3(o));
            }
        }
        if (ph == 1) {
          #pragma unroll
          for (int fn = 0; fn < 2; ++fn)
            #pragma unroll
            for (int kh = 0; kh < 2; ++kh) {
              int o = (wn * 64 + 32 + fn * 16 + llo) * 128 + kh * 64 + lhi * 16;
              b1R[fn][kh] = *(const short8*)(LDS + 65536 + buf * 32768 + swz3(o));
            }
        }
        const int P = kk * 4 + ph;
        if      (P == 0) stA(1, 0, 2 * i + 1);
        else if (P == 1) stA(1, 1, 2 * i + 1);
        else if (P == 2) { if (!last) stB(0, 0, 2 * i + 2); }
        else if (P == 3) { if (!last) stB(0, 1, 2 * i + 2); }
        else if (P == 4) { if (!last) stA(0, 0, 2 * i + 2); }
        else if (P == 5) { if (!last) stA(0, 1, 2 * i + 2); }
        else if (P == 6) { if (!last) stB(1, 0, 2 * i + 3); }
        else if (P == 7) { if (!last) stB(1, 1, 2 * i + 3); }
        if (P == 3) { if (last) { VMC(0); } else { VMC(4); } }
        if (P == 7) { if (!last) { VMC(4); } }
        BAR();
        WAITL0();
        __builtin_amdgcn_sched_barrier(0);
        __builtin_amdgcn_s_setprio(1);
        #pragma unroll
        for (int kh = 0; kh < 2; ++kh)
          #pragma unroll
          for (int fm = 0; fm < 4; ++fm)
            #pragma unroll
            for (int fn = 0; fn < 2; ++fn)
              acc[h * 4 + fm][nh * 2 + fn] = __builtin_amdgcn_mfma_f32_16x16x32_bf16(
                  aR[fm][kh], nh ? b1R[fn][kh] : b0R[fn][kh],
                  acc[h * 4 + fm][nh * 2 + fn], 0, 0, 0);
        __builtin_amdgcn_s_setprio(0);
        BAR();
      }
    }
  };

  for (int i = 0; i < NITER - 1; ++i) ITER(i, false);
  ITER(NITER - 1, true);

  // ---- epilogues (C/D: col = lane&15, row = (lane>>4)*4 + r). LDS is dead
  // after the final BAR (all ds_reads consumed pre-MFMA) -> reuse as scratch.
  if constexpr (VAR == 0) {
    float* gredF = (float*)LDS;           // [256][4]
    float b1v[4], w2v[4];
    #pragma unroll
    for (int FN = 0; FN < 4; ++FN) {
      int colg = bcol + wn * 64 + FN * 16 + llo;
      b1v[FN] = bias[colg]; w2v[FN] = W2[colg];
    }
    #pragma unroll
    for (int FM = 0; FM < 8; ++FM)
      #pragma unroll
      for (int r = 0; r < 4; ++r) {
        float part = 0.f;
        #pragma unroll
        for (int FN = 0; FN < 4; ++FN)
          part += tanhf(acc[FM][FN][r] + b1v[FN]) * w2v[FN];
        part += __shfl_xor(part, 1);
        part += __shfl_xor(part, 2);
        part += __shfl_xor(part, 4);
        part += __shfl_xor(part, 8);
        if (llo == 0) gredF[(wm * 128 + FM * 16 + lhi * 4 + r) * 4 + wn] = part;
      }
    __syncthreads();
    if (tid < 256)
      pg[(size_t)bx * 16384 + brow + tid] =
          gredF[tid * 4 + 0] + gredF[tid * 4 + 1] + gredF[tid * 4 + 2] + gredF[tid * 4 + 3];
  }
  if constexpr (VAR == 1) {
    const float rs = 0.02209708691207961f;  // 1/sqrt(2048)
    unsigned short* C16 = reinterpret_cast<unsigned short*>(Cf);
    float cs[4] = {0.f, 0.f, 0.f, 0.f};
    #pragma unroll
    for (int FM = 0; FM < 8; ++FM)
      #pragma unroll
      for (int r = 0; r < 4; ++r) {
        size_t R = (size_t)z * SEQ + (brow + wm * 128 + FM * 16 + lhi * 4 + r);
        #pragma unroll
        for (int FN = 0; FN < 4; ++FN) {
          int col = bcol + wn * 64 + FN * 16 + llo;
          unsigned short us = f2bf(acc[FM][FN][r] * rs);
          C16[R * 4096 + col] = us;
          cs[FN] += __expf(bf2f(us));     // exp of the STORED bf16 score
        }
      }
    float* cp = (float*)LDS;              // [2][256]
    #pragma unroll
    for (int FN = 0; FN < 4; ++FN) {
      cs[FN] += __shfl_xor(cs[FN], 16);
      cs[FN] += __shfl_xor(cs[FN], 32);
      if (lhi == 0) cp[wm * 256 + wn * 64 + FN * 16 + llo] = cs[FN];
    }
    __syncthreads();
    if (tid < 256)
      pl[(size_t)by * 16384 + z * 2048 + bcol + tid] = cp[tid] + cp[256 + tid];
  }
  if constexpr (VAR == 2) {
    float* C = Cf + (size_t)z * SEQ * DIM;
    const float* Q = qres + (size_t)z * SEQ * DIM;
    #pragma unroll
    for (int FM = 0; FM < 8; ++FM)
      #pragma unroll
      for (int r = 0; r < 4; ++r) {
        int rowg = brow + wm * 128 + FM * 16 + lhi * 4 + r;
        #pragma unroll
        for (int FN = 0; FN < 4; ++FN) {
          int colg = bcol + wn * 64 + FN * 16 + llo;
          C[(size_t)rowg * DIM + colg] = acc[FM][FN][r] + Q[(size_t)rowg * DIM + colg];
        }
      }
  }
}

// ---------------------------------------------------------------------------
// Fallback PV GEMM (f32 weights + f32 v), single-buffer — only if ws too small.
// ---------------------------------------------------------------------------
__global__ __launch_bounds__(256)
void gemm_slow(const float* __restrict__ Wf, const float* __restrict__ Vf,
               const float* __restrict__ qres, float* __restrict__ Cf)
{
  __shared__ __align__(16) unsigned short AsL[128 * 64];
  __shared__ __align__(16) unsigned short BsL[128 * 32];

  const int tid  = threadIdx.x;
  const int z    = blockIdx.z;
  const int brow = blockIdx.y * 128;
  const int bcol = blockIdx.x * 128;
  const int lane = tid & 63;
  const int wid  = tid >> 6;
  const int wr   = (wid >> 1) * 64;
  const int wc   = (wid & 1) * 64;
  const int lhi  = lane >> 4;
  const int llo  = lane & 15;

  const float* AsrcF = Wf + (size_t)z * SEQ * SEQ + (size_t)brow * SEQ;
  const float* BsrcF = Vf + (size_t)z * SEQ * DIM;

  f32x4 acc[4][4];
  #pragma unroll
  for (int m = 0; m < 4; ++m)
    #pragma unroll
    for (int n = 0; n < 4; ++n)
      acc[m][n] = (f32x4)(0.0f);

  for (int k0 = 0; k0 < SEQ; k0 += 32) {
    #pragma unroll
    for (int i = 0; i < 4; ++i) {
      int ob = wid * 4096 + i * 1024;
      int a  = swz3(ob + lane * 16);
      gll16((const char*)AsrcF + (size_t)(a >> 7) * (SEQ * 4) + (size_t)k0 * 4 + (a & 127),
            (char*)AsL + ob);
    }
    {
      int n4 = (tid & 31) << 2;
      int kb = (tid >> 5) << 2;
      float4 r0 = *(const float4*)(BsrcF + (size_t)(k0 + kb + 0) * DIM + bcol + n4);
      float4 r1 = *(const float4*)(BsrcF + (size_t)(k0 + kb + 1) * DIM + bcol + n4);
      float4 r2 = *(const float4*)(BsrcF + (size_t)(k0 + kb + 2) * DIM + bcol + n4);
      float4 r3 = *(const float4*)(BsrcF + (size_t)(k0 + kb + 3) * DIM + bcol + n4);
      float a0[4] = {r0.x, r0.y, r0.z, r0.w};
      float a1[4] = {r1.x, r1.y, r1.z, r1.w};
      float a2[4] = {r2.x, r2.y, r2.z, r2.w};
      float a3[4] = {r3.x, r3.y, r3.z, r3.w};
      #pragma unroll
      for (int jj = 0; jj < 4; ++jj) {
        unsigned lo = (__float_as_uint(a0[jj]) >> 16) | (__float_as_uint(a1[jj]) & 0xFFFF0000u);
        unsigned hi = (__float_as_uint(a2[jj]) >> 16) | (__float_as_uint(a3[jj]) & 0xFFFF0000u);
        int ol = (n4 + jj) * 64 + kb * 2;
        *(uint2*)((char*)BsL + swz2(ol)) = make_uint2(lo, hi);
      }
    }
    __syncthreads();

    short8 af[4], bfr[4];
    #pragma unroll
    for (int m = 0; m < 4; ++m) {
      int row = wr + m * 16 + llo;
      int a0i = row * 128 + lhi * 32;
      f32x4 x = *(const f32x4*)((const char*)AsL + swz3(a0i));
      f32x4 y = *(const f32x4*)((const char*)AsL + swz3(a0i + 16));
      union { unsigned u[4]; short8 s; } r;
      r.u[0] = (__float_as_uint(x[0]) >> 16) | (__float_as_uint(x[1]) & 0xFFFF0000u);
      r.u[1] = (__float_as_uint(x[2]) >> 16) | (__float_as_uint(x[3]) & 0xFFFF0000u);
      r.u[2] = (__float_as_uint(y[0]) >> 16) | (__float_as_uint(y[1]) & 0xFFFF0000u);
      r.u[3] = (__float_as_uint(y[2]) >> 16) | (__float_as_uint(y[3]) & 0xFFFF0000u);
      af[m] = r.s;
    }
    #pragma unroll
    for (int n = 0; n < 4; ++n) {
      int a = (wc + n * 16 + llo) * 64 + lhi * 16;
      bfr[n] = *(const short8*)((const char*)BsL + swz2(a));
    }
    #pragma unroll
    for (int m = 0; m < 4; ++m)
      #pragma unroll
      for (int n = 0; n < 4; ++n)
        acc[m][n] = __builtin_amdgcn_mfma_f32_16x16x32_bf16(af[m], bfr[n], acc[m][n], 0, 0, 0);
    __syncthreads();
  }

  float* C = Cf + (size_t)z * SEQ * DIM;
  const float* Q = qres + (size_t)z * SEQ * DIM;
  #pragma unroll
  for (int m = 0; m < 4; ++m)
    #pragma unroll
    for (int r = 0; r < 4; ++r) {
      int rowg = brow + wr + m * 16 + lhi * 4 + r;
      #pragma unroll
      for (int n = 0; n < 4; ++n) {
        int colg = bcol + wc + n * 16 + llo;
        C[(size_t)rowg * DIM + colg] = acc[m][n][r] + Q[(size_t)rowg * DIM + colg];
      }
    }
}

// ---------------------------------------------------------------------------
// Fused prepack: per 64x64 tile of each [2048x768] batch matrix,
// q -> qb, k -> kb slot, v -> vb slot AND v^T -> vT (LDS transpose).
// ---------------------------------------------------------------------------
__global__ __launch_bounds__(256)
void prepack_fused(const float* __restrict__ q, const float* __restrict__ k,
                   const float* __restrict__ v, unsigned short* __restrict__ qb,
                   unsigned short* __restrict__ wsl, unsigned short* __restrict__ vT,
                   int dovT)
{
  __shared__ unsigned short T[64][66];
  const int z  = blockIdx.z;
  const int r0 = blockIdx.y * 64, c0 = blockIdx.x * 64;
  const size_t mb = (size_t)z * SEQ * DIM;
  const int t16 = threadIdx.x & 15, trw = threadIdx.x >> 4;

  #pragma unroll
  for (int j = 0; j < 4; ++j) {
    int row = j * 16 + trw;
    size_t e = mb + (size_t)(r0 + row) * DIM + c0 + t16 * 4;
    float4 qv = *(const float4*)(q + e);
    float4 kv = *(const float4*)(k + e);
    float4 vv = *(const float4*)(v + e);
    ushort4 qo; qo.x = f2bf(qv.x); qo.y = f2bf(qv.y); qo.z = f2bf(qv.z); qo.w = f2bf(qv.w);
    ushort4 ko; ko.x = f2bf(kv.x); ko.y = f2bf(kv.y); ko.z = f2bf(kv.z); ko.w = f2bf(kv.w);
    ushort4 vo; vo.x = f2bf(vv.x); vo.y = f2bf(vv.y); vo.z = f2bf(vv.z); vo.w = f2bf(vv.w);
    *(ushort4*)(qb + e) = qo;
    size_t so = (size_t)(z * SEQ + r0 + row) * 4096 + 2048 + c0 + t16 * 4;
    *(ushort4*)(wsl + so) = ko;
    *(ushort4*)(wsl + so + DIM) = vo;
    // stash v tile for transpose (two 4B stores: row stride 132B keeps 4B align)
    *(unsigned*)&T[row][t16 * 4]     = (unsigned)vo.x | ((unsigned)vo.y << 16);
    *(unsigned*)&T[row][t16 * 4 + 2] = (unsigned)vo.z | ((unsigned)vo.w << 16);
  }
  __syncthreads();
  if (dovT) {
    const int tc = threadIdx.x & 63, tr2 = threadIdx.x >> 6;
    unsigned short* vTm = vT + (size_t)z * DIM * SEQ;
    #pragma unroll
    for (int j = 0; j < 16; ++j) {
      int orow = j * 4 + tr2;   // original column index within tile
      vTm[(size_t)(c0 + orow) * SEQ + r0 + tc] = T[tc][orow];
    }
  }
}

// [R][C] f32 -> [C][R] bf16 (W1 only)
__global__ __launch_bounds__(256)
void transpose_f32_bf16(const float* __restrict__ src, unsigned short* __restrict__ dst,
                        int R, int C)
{
  __shared__ unsigned short T[64][65];
  int r0 = blockIdx.y * 64, c0 = blockIdx.x * 64;
  int tr = threadIdx.x >> 6, tc = threadIdx.x & 63;
  #pragma unroll
  for (int j = 0; j < 16; ++j) {
    int row = j * 4 + tr;
    T[row][tc] = f2bf(src[(size_t)(r0 + row) * C + c0 + tc]);
  }
  __syncthreads();
  #pragma unroll
  for (int j = 0; j < 16; ++j) {
    int row = j * 4 + tr;
    dst[(size_t)(c0 + row) * R + r0 + tc] = T[tc][row];
  }
}

// lcol = sum of 8 row-block exp partials; g = b2 + 2 gate col-block partials
__global__ void finalize(const float* __restrict__ pl, const float* __restrict__ pg,
                         const float* __restrict__ b2, float* __restrict__ lcol,
                         float* __restrict__ g)
{
  int i = blockIdx.x * 256 + threadIdx.x;
  float l = 0.f;
  #pragma unroll
  for (int ch = 0; ch < 8; ++ch) l += pl[ch * 16384 + i];
  lcol[i] = l;
  g[i] = b2[0] + pg[i] + pg[16384 + i];
}

// Row pass: s = exp(x)/lcol; t = (s*(1-g) + g/S)/sqrt(768); row softmax.
// In-place bf16->f32; optional bf16 weights copy (FAST tier).
template<bool FAST>
__global__ __launch_bounds__(256)
void rowpass(float* __restrict__ w, const float* __restrict__ lcol,
             const float* __restrict__ gg, unsigned short* __restrict__ wb)
{
  const size_t row = blockIdx.x;
  const int b = (int)(row >> 11);
  const unsigned short* p = (const unsigned short*)w + row * 4096;
  float* wrow = w + row * 2048;
  const int c0 = threadIdx.x * 8;
  const float* lc = lcol + (b << 11);
  const float* gb = gg + (b << 11);

  unsigned short xs[8];
  *(ushort4*)&xs[0] = *(const ushort4*)(p + c0);
  *(ushort4*)&xs[4] = *(const ushort4*)(p + c0 + 4);
  float ls[8], gs[8];
  *(float4*)&ls[0] = *(const float4*)(lc + c0);
  *(float4*)&ls[4] = *(const float4*)(lc + c0 + 4);
  *(float4*)&gs[0] = *(const float4*)(gb + c0);
  *(float4*)&gs[4] = *(const float4*)(gb + c0 + 4);

  float e[8];
  float psum = 0.f;
  #pragma unroll
  for (int j = 0; j < 8; ++j) {
    float s = __expf(bf2f(xs[j])) / ls[j];
    float t = (s * (1.f - gs[j]) + gs[j] * (1.f / 2048.f)) * 0.03608439182435161f;
    float ev = __expf(t);
    e[j] = ev;
    psum += ev;
  }
  #pragma unroll
  for (int off = 1; off < 64; off <<= 1) psum += __shfl_xor(psum, off);
  __shared__ float red[4];
  if ((threadIdx.x & 63) == 0) red[threadIdx.x >> 6] = psum;
  __syncthreads();
  float inv = 1.f / (red[0] + red[1] + red[2] + red[3]);
  float4 o0, o1;
  o0.x = e[0] * inv; o0.y = e[1] * inv; o0.z = e[2] * inv; o0.w = e[3] * inv;
  o1.x = e[4] * inv; o1.y = e[5] * inv; o1.z = e[6] * inv; o1.w = e[7] * inv;
  *(float4*)(wrow + c0) = o0;
  *(float4*)(wrow + c0 + 4) = o1;
  if constexpr (FAST) {
    ushort4 b0, b1v;
    b0.x = f2bf(o0.x); b0.y = f2bf(o0.y); b0.z = f2bf(o0.z); b0.w = f2bf(o0.w);
    b1v.x = f2bf(o1.x); b1v.y = f2bf(o1.y); b1v.z = f2bf(o1.z); b1v.w = f2bf(o1.w);
    *(ushort4*)(wb + row * 2048 + c0) = b0;
    *(ushort4*)(wb + row * 2048 + c0 + 4) = b1v;
  }
}

extern "C" void kernel_launch(void* const* d_in, const int* in_sizes, int n_in,
                              void* d_out, int out_size, void* d_ws, size_t ws_size,
                              hipStream_t stream)
{
  (void)in_sizes; (void)n_in; (void)out_size;
  const float* q  = (const float*)d_in[0];
  const float* k  = (const float*)d_in[1];
  const float* v  = (const float*)d_in[2];
  const float* W1 = (const float*)d_in[3];
  const float* b1 = (const float*)d_in[4];
  const float* W2 = (const float*)d_in[5];
  const float* b2 = (const float*)d_in[6];

  float* out0 = (float*)d_out;                       // [B,S,D] f32 (holds qb until PV)
  float* wbuf = out0 + (size_t)BATCH * SEQ * DIM;    // [B,S,S] f32 weights slots
  unsigned short* wsl = (unsigned short*)wbuf;       // slot view (lower: scores, upper: kb/vb)
  unsigned short* qb  = (unsigned short*)out0;

  float* g    = (float*)d_ws;                        // 16384
  float* lcol = g + 16384;                           // 16384
  float* pg   = lcol + 16384;                        // 65536 (2 used)
  float* pl   = pg + 65536;                          // 262144 (8*16384 used)
  unsigned short* W1T = (unsigned short*)(pl + 262144);            // 393216 ushorts
  unsigned short* vT  = (unsigned short*)((char*)d_ws + 2228224);  // 12.58M ushorts
  unsigned short* wb  = vT + (size_t)12582912;                     // 33.55M ushorts
  const bool fast = ws_size >= 94502912ull;

  prepack_fused<<<dim3(12, 32, 8), 256, 0, stream>>>(q, k, v, qb, wsl, vT, fast ? 1 : 0);
  transpose_f32_bf16<<<dim3(8, 12, 1), 256, 0, stream>>>(W1, W1T, 768, 512);

  // gate: 8-phase 256^2, fused tanh/W2 epilogue -> pg
  gemm8<0><<<128, 512, 0, stream>>>(wsl + 2816, W1T, nullptr, nullptr, b1, W2, pg, nullptr);
  // scores: 8-phase 256^2 -> bf16 into weight-row slots + column exp-sum partials
  gemm8<1><<<512, 512, 0, stream>>>(qb, wsl, nullptr, wbuf, nullptr, nullptr, nullptr, pl);

  finalize<<<64, 256, 0, stream>>>(pl, pg, b2, lcol, g);

  if (fast) {
    rowpass<true><<<16384, 256, 0, stream>>>(wbuf, lcol, g, wb);
    gemm8<2><<<192, 512, 0, stream>>>(wb, vT, q, out0, nullptr, nullptr, nullptr, nullptr);
  } else {
    rowpass<false><<<16384, 256, 0, stream>>>(wbuf, lcol, g, nullptr);
    gemm_slow<<<dim3(6, 16, 8), 256, 0, stream>>>(wbuf, v, q, out0);
  }
}

// Round 7
// 253.416 us; speedup vs baseline: 1.7929x; 1.0296x over previous
//
#include <hip/hip_runtime.h>

#define BATCH 8
#define SEQ   2048
#define DIM   768
#define HID   512

typedef __attribute__((ext_vector_type(8))) short  short8;
typedef __attribute__((ext_vector_type(4))) float  f32x4;

#define BAR()    asm volatile("s_barrier" ::: "memory")
#define WAITL0() asm volatile("s_waitcnt lgkmcnt(0)" ::: "memory")
#define VMC(n)   asm volatile("s_waitcnt vmcnt(" #n ")" ::: "memory")

__device__ __forceinline__ unsigned short f2bf(float f) {
  union { float f; unsigned u; } x; x.f = f;
  return (unsigned short)((x.u + 0x7FFFu + ((x.u >> 16) & 1u)) >> 16);
}
__device__ __forceinline__ float bf2f(unsigned short u) {
  union { unsigned u; float f; } x; x.u = ((unsigned)u) << 16;
  return x.f;
}
__device__ __forceinline__ void gll16(const void* g, void* l) {
  __builtin_amdgcn_global_load_lds(
      (const __attribute__((address_space(1))) void*)g,
      (__attribute__((address_space(3))) void*)l, 16, 0, 0);
}
// XOR swizzles (involutions; keep bits 0-3 so 16B chunks stay contiguous)
__device__ __forceinline__ int swz2(int o) { return o ^ (((o >> 8) & 7) << 4); }  // 64B rows
__device__ __forceinline__ int swz3(int o) { return o ^ (((o >> 7) & 7) << 4); }  // 128B rows

// ---------------------------------------------------------------------------
// 8-phase 256x256 BK=64 bf16 GEMM (scores). Proven in rounds 5/6. Grid 512
// = 2 exact waves of 256 CUs. Epilogue: bf16 scores + column exp-sum partials.
// ---------------------------------------------------------------------------
template<int VAR>
__global__ __launch_bounds__(512, 2)
void gemm8(const unsigned short* __restrict__ Ap, const unsigned short* __restrict__ Bp,
           const float* __restrict__ qres, float* __restrict__ Cf,
           const float* __restrict__ bias, const float* __restrict__ W2,
           float* __restrict__ pg, float* __restrict__ pl)
{
  constexpr int K     = (VAR == 2) ? SEQ : DIM;
  constexpr int NT    = K / 64;
  constexpr int NITER = NT / 2;
  constexpr int APB   = (VAR == 0) ? 8192 : (VAR == 1 ? 1536 : 4096);
  constexpr int BPB   = (VAR == 0) ? 1536 : (VAR == 1 ? 8192 : 4096);
  constexpr int GX    = (VAR == 0) ? 2 : (VAR == 1 ? 8 : 3);
  constexpr int GY    = (VAR == 0) ? 64 : 8;
  constexpr int NB    = (VAR == 0) ? 1 : BATCH;
  constexpr int NWG   = GX * GY * NB;

  __shared__ __align__(16) unsigned char LDS[131072];   // A: 2x32K @0, B: 2x32K @64K

  int wg = ((blockIdx.x & 7) * (NWG >> 3)) + ((int)blockIdx.x >> 3);
  const int z  = wg / (GX * GY);
  const int r2 = wg % (GX * GY);
  const int by = r2 / GX;
  const int bx = r2 % GX;
  const int brow = by * 256, bcol = bx * 256;

  const int tid  = threadIdx.x;
  const int lane = tid & 63, wid = tid >> 6;
  const int wm   = wid >> 2, wn = wid & 3;
  const int lhi  = lane >> 4, llo = lane & 15;

  const char* Abase;
  const char* Bbase;
  if constexpr (VAR == 0) {
    Abase = (const char*)Ap + (size_t)brow * APB;
    Bbase = (const char*)Bp + (size_t)bcol * BPB;
  } else if constexpr (VAR == 1) {
    Abase = (const char*)(Ap + (size_t)z * SEQ * DIM) + (size_t)brow * APB;
    Bbase = (const char*)(Bp + (size_t)z * SEQ * 4096 + 2048) + (size_t)bcol * BPB;
  } else {
    Abase = (const char*)(Ap + (size_t)z * SEQ * SEQ) + (size_t)brow * APB;
    Bbase = (const char*)(Bp + (size_t)z * (size_t)DIM * SEQ) + (size_t)bcol * BPB;
  }

  int sr[2], sk[2];
  #pragma unroll
  for (int c = 0; c < 2; ++c) {
    int o = wid * 2048 + c * 1024 + lane * 16;
    int a = swz3(o);
    sr[c] = a >> 7; sk[c] = a & 127;
  }
  auto stA = [&](int buf, int hh, int t) {
    #pragma unroll
    for (int c = 0; c < 2; ++c)
      gll16(Abase + (size_t)(hh * 128 + sr[c]) * APB + t * 128 + sk[c],
            LDS + buf * 32768 + hh * 16384 + wid * 2048 + c * 1024);
  };
  auto stB = [&](int buf, int hh, int t) {
    #pragma unroll
    for (int c = 0; c < 2; ++c)
      gll16(Bbase + (size_t)(hh * 128 + sr[c]) * BPB + t * 128 + sk[c],
            LDS + 65536 + buf * 32768 + hh * 16384 + wid * 2048 + c * 1024);
  };

  f32x4 acc[8][4];
  #pragma unroll
  for (int m = 0; m < 8; ++m)
    #pragma unroll
    for (int n = 0; n < 4; ++n)
      acc[m][n] = (f32x4)(0.0f);

  stA(0, 0, 0); stA(0, 1, 0); stB(0, 0, 0); stB(0, 1, 0);
  stB(1, 0, 1); stB(1, 1, 1);
  VMC(4);
  BAR();

  auto ITER = [&](int i, bool last) {
    #pragma unroll
    for (int kk = 0; kk < 2; ++kk) {
      const int buf = kk;
      short8 aR[4][2], b0R[2][2], b1R[2][2];
      #pragma unroll
      for (int ph = 0; ph < 4; ++ph) {
        const int h  = ph >> 1;
        const int nh = (ph == 1 || ph == 2) ? 1 : 0;
        if (ph == 0 || ph == 2) {
          #pragma unroll
          for (int fm = 0; fm < 4; ++fm)
            #pragma unroll
            for (int kh = 0; kh < 2; ++kh) {
              int o = (wm * 128 + h * 64 + fm * 16 + llo) * 128 + kh * 64 + lhi * 16;
              aR[fm][kh] = *(const short8*)(LDS + buf * 32768 + swz3(o));
            }
        }
        if (ph == 0) {
          #pragma unroll
          for (int fn = 0; fn < 2; ++fn)
            #pragma unroll
            for (int kh = 0; kh < 2; ++kh) {
              int o = (wn * 64 + fn * 16 + llo) * 128 + kh * 64 + lhi * 16;
              b0R[fn][kh] = *(const short8*)(LDS + 65536 + buf * 32768 + swz3(o));
            }
        }
        if (ph == 1) {
          #pragma unroll
          for (int fn = 0; fn < 2; ++fn)
            #pragma unroll
            for (int kh = 0; kh < 2; ++kh) {
              int o = (wn * 64 + 32 + fn * 16 + llo) * 128 + kh * 64 + lhi * 16;
              b1R[fn][kh] = *(const short8*)(LDS + 65536 + buf * 32768 + swz3(o));
            }
        }
        const int P = kk * 4 + ph;
        if      (P == 0) stA(1, 0, 2 * i + 1);
        else if (P == 1) stA(1, 1, 2 * i + 1);
        else if (P == 2) { if (!last) stB(0, 0, 2 * i + 2); }
        else if (P == 3) { if (!last) stB(0, 1, 2 * i + 2); }
        else if (P == 4) { if (!last) stA(0, 0, 2 * i + 2); }
        else if (P == 5) { if (!last) stA(0, 1, 2 * i + 2); }
        else if (P == 6) { if (!last) stB(1, 0, 2 * i + 3); }
        else if (P == 7) { if (!last) stB(1, 1, 2 * i + 3); }
        if (P == 3) { if (last) { VMC(0); } else { VMC(4); } }
        if (P == 7) { if (!last) { VMC(4); } }
        BAR();
        WAITL0();
        __builtin_amdgcn_sched_barrier(0);
        __builtin_amdgcn_s_setprio(1);
        #pragma unroll
        for (int kh = 0; kh < 2; ++kh)
          #pragma unroll
          for (int fm = 0; fm < 4; ++fm)
            #pragma unroll
            for (int fn = 0; fn < 2; ++fn)
              acc[h * 4 + fm][nh * 2 + fn] = __builtin_amdgcn_mfma_f32_16x16x32_bf16(
                  aR[fm][kh], nh ? b1R[fn][kh] : b0R[fn][kh],
                  acc[h * 4 + fm][nh * 2 + fn], 0, 0, 0);
        __builtin_amdgcn_s_setprio(0);
        BAR();
      }
    }
  };

  for (int i = 0; i < NITER - 1; ++i) ITER(i, false);
  ITER(NITER - 1, true);

  if constexpr (VAR == 1) {
    const float rs = 0.02209708691207961f;  // 1/sqrt(2048)
    unsigned short* C16 = reinterpret_cast<unsigned short*>(Cf);
    float cs[4] = {0.f, 0.f, 0.f, 0.f};
    #pragma unroll
    for (int FM = 0; FM < 8; ++FM)
      #pragma unroll
      for (int r = 0; r < 4; ++r) {
        size_t R = (size_t)z * SEQ + (brow + wm * 128 + FM * 16 + lhi * 4 + r);
        #pragma unroll
        for (int FN = 0; FN < 4; ++FN) {
          int col = bcol + wn * 64 + FN * 16 + llo;
          unsigned short us = f2bf(acc[FM][FN][r] * rs);
          C16[R * 4096 + col] = us;
          cs[FN] += __expf(bf2f(us));
        }
      }
    float* cp = (float*)LDS;
    #pragma unroll
    for (int FN = 0; FN < 4; ++FN) {
      cs[FN] += __shfl_xor(cs[FN], 16);
      cs[FN] += __shfl_xor(cs[FN], 32);
      if (lhi == 0) cp[wm * 256 + wn * 64 + FN * 16 + llo] = cs[FN];
    }
    __syncthreads();
    if (tid < 256)
      pl[(size_t)by * 16384 + z * 2048 + bcol + tid] = cp[tid] + cp[256 + tid];
  }
}

// ---------------------------------------------------------------------------
// Gate GEMM, 8-phase 256x128 BK=64. Grid 256 = exactly 1 round of 256 CUs.
// A = vb slots (pitch 8192B), B = W1T (pitch 1536B), K=768. LDS 96K.
// B half-tile = 64 rows = 1 gll/thread -> gates vmcnt(2).
// Epilogue: tanh(acc+b1)*W2 row-reduce -> pg[4][16384] (4 col-block partials).
// ---------------------------------------------------------------------------
__global__ __launch_bounds__(512, 2)
void gemm_gate8(const unsigned short* __restrict__ Ap, const unsigned short* __restrict__ Bp,
                const float* __restrict__ bias, const float* __restrict__ W2,
                float* __restrict__ pg)
{
  constexpr int NITER = 6;   // K=768 -> 12 BK=64 tiles
  __shared__ __align__(16) unsigned char LDS[98304];  // A 2x32K @0, B 2x16K @65536

  int wg = ((blockIdx.x & 7) * 32) + ((int)blockIdx.x >> 3);
  const int by = wg >> 2, bx = wg & 3;
  const int brow = by * 256, bcol = bx * 128;

  const int tid  = threadIdx.x;
  const int lane = tid & 63, wid = tid >> 6;
  const int wm   = wid >> 2, wn = wid & 3;
  const int lhi  = lane >> 4, llo = lane & 15;

  const char* Abase = (const char*)Ap + (size_t)brow * 8192;
  const char* Bbase = (const char*)Bp + (size_t)bcol * 1536;

  int srA[2], skA[2];
  #pragma unroll
  for (int c = 0; c < 2; ++c) {
    int o = wid * 2048 + c * 1024 + lane * 16;
    int a = swz3(o);
    srA[c] = a >> 7; skA[c] = a & 127;
  }
  const int o1 = tid * 16;
  const int a1 = swz3(o1);
  const int sr1 = a1 >> 7, sk1 = a1 & 127;

  auto stA = [&](int buf, int hh, int t) {
    #pragma unroll
    for (int c = 0; c < 2; ++c)
      gll16(Abase + (size_t)(hh * 128 + srA[c]) * 8192 + t * 128 + skA[c],
            LDS + buf * 32768 + hh * 16384 + wid * 2048 + c * 1024);
  };
  auto stB = [&](int buf, int hh, int t) {
    gll16(Bbase + (size_t)(hh * 64 + sr1) * 1536 + t * 128 + sk1,
          LDS + 65536 + buf * 16384 + hh * 8192 + wid * 1024);
  };

  f32x4 acc[8][2];
  #pragma unroll
  for (int m = 0; m < 8; ++m)
    #pragma unroll
    for (int n = 0; n < 2; ++n)
      acc[m][n] = (f32x4)(0.0f);

  // prologue: tile0 (A 4 gll + B 2 gll) + tile1 B (2 gll)
  stA(0, 0, 0); stA(0, 1, 0); stB(0, 0, 0); stB(0, 1, 0);
  stB(1, 0, 1); stB(1, 1, 1);
  VMC(2);
  BAR();

  auto ITER = [&](int i, bool last) {
    #pragma unroll
    for (int kk = 0; kk < 2; ++kk) {
      const int buf = kk;
      short8 aR[4][2], b0R[2], b1R[2];
      #pragma unroll
      for (int ph = 0; ph < 4; ++ph) {
        const int h  = ph >> 1;
        const int nh = (ph == 1 || ph == 2) ? 1 : 0;
        if (ph == 0 || ph == 2) {
          #pragma unroll
          for (int fm = 0; fm < 4; ++fm)
            #pragma unroll
            for (int kh = 0; kh < 2; ++kh) {
              int o = (wm * 128 + h * 64 + fm * 16 + llo) * 128 + kh * 64 + lhi * 16;
              aR[fm][kh] = *(const short8*)(LDS + buf * 32768 + swz3(o));
            }
        }
        if (ph == 0) {
          #pragma unroll
          for (int kh = 0; kh < 2; ++kh) {
            int o = (wn * 32 + llo) * 128 + kh * 64 + lhi * 16;
            b0R[kh] = *(const short8*)(LDS + 65536 + buf * 16384 + swz3(o));
          }
        }
        if (ph == 1) {
          #pragma unroll
          for (int kh = 0; kh < 2; ++kh) {
            int o = (wn * 32 + 16 + llo) * 128 + kh * 64 + lhi * 16;
            b1R[kh] = *(const short8*)(LDS + 65536 + buf * 16384 + swz3(o));
          }
        }
        const int P = kk * 4 + ph;
        if      (P == 0) stA(1, 0, 2 * i + 1);
        else if (P == 1) stA(1, 1, 2 * i + 1);
        else if (P == 2) { if (!last) stB(0, 0, 2 * i + 2); }
        else if (P == 3) { if (!last) stB(0, 1, 2 * i + 2); }
        else if (P == 4) { if (!last) stA(0, 0, 2 * i + 2); }
        else if (P == 5) { if (!last) stA(0, 1, 2 * i + 2); }
        else if (P == 6) { if (!last) stB(1, 0, 2 * i + 3); }
        else if (P == 7) { if (!last) stB(1, 1, 2 * i + 3); }
        if (P == 3) { if (last) { VMC(0); } else { VMC(2); } }
        if (P == 7) { if (!last) { VMC(2); } }
        BAR();
        WAITL0();
        __builtin_amdgcn_sched_barrier(0);
        __builtin_amdgcn_s_setprio(1);
        #pragma unroll
        for (int kh = 0; kh < 2; ++kh)
          #pragma unroll
          for (int fm = 0; fm < 4; ++fm)
            acc[h * 4 + fm][nh] = __builtin_amdgcn_mfma_f32_16x16x32_bf16(
                aR[fm][kh], nh ? b1R[kh] : b0R[kh], acc[h * 4 + fm][nh], 0, 0, 0);
        __builtin_amdgcn_s_setprio(0);
        BAR();
      }
    }
  };

  for (int i = 0; i < NITER - 1; ++i) ITER(i, false);
  ITER(NITER - 1, true);

  // epilogue: fused tanh/W2 reduce (C/D: col = lane&15, row = (lane>>4)*4+r)
  float* gredF = (float*)LDS;   // [256][4]
  float b1v[2], w2v[2];
  #pragma unroll
  for (int FN = 0; FN < 2; ++FN) {
    int colg = bcol + wn * 32 + FN * 16 + llo;
    b1v[FN] = bias[colg]; w2v[FN] = W2[colg];
  }
  #pragma unroll
  for (int FM = 0; FM < 8; ++FM)
    #pragma unroll
    for (int r = 0; r < 4; ++r) {
      float part = tanhf(acc[FM][0][r] + b1v[0]) * w2v[0]
                 + tanhf(acc[FM][1][r] + b1v[1]) * w2v[1];
      part += __shfl_xor(part, 1);
      part += __shfl_xor(part, 2);
      part += __shfl_xor(part, 4);
      part += __shfl_xor(part, 8);
      if (llo == 0) gredF[(wm * 128 + FM * 16 + lhi * 4 + r) * 4 + wn] = part;
    }
  __syncthreads();
  if (tid < 256)
    pg[(size_t)bx * 16384 + brow + tid] =
        gredF[tid * 4 + 0] + gredF[tid * 4 + 1] + gredF[tid * 4 + 2] + gredF[tid * 4 + 3];
}

// ---------------------------------------------------------------------------
// PV GEMM, 4-phase 128x192 BK=64, 8 waves (2M x 4N), LDS 80K -> 2 blocks/CU.
// Grid 512 (16 M x 4 N x 8 batch) = exact multiple of capacity at 1 or 2/CU.
// A tile = 2 staging units, B = 3 units (64 rows x 128B = 1 gll/thread each).
// Stage map P0:A(1) P1:B(0,t+2) P2:A(0,t+2) P3:B(1,t+3); gates vmcnt(3) at
// P1/P3. K order identical to previous PV -> bit-identical output.
// ---------------------------------------------------------------------------
__global__ __launch_bounds__(512, 4)
void gemm_pv(const unsigned short* __restrict__ Ap, const unsigned short* __restrict__ Bp,
             const float* __restrict__ qres, float* __restrict__ Cf)
{
  constexpr int NITER = 16;  // K=2048 -> 32 BK=64 tiles
  __shared__ __align__(16) unsigned char LDS[81920];  // A 2x16K @0, B 2x24K @32768

  int wg = ((blockIdx.x & 7) * 64) + ((int)blockIdx.x >> 3);
  const int z  = wg >> 6;
  const int r2 = wg & 63;
  const int by = r2 >> 2, bx = r2 & 3;
  const int brow = by * 128, bcol = bx * 192;

  const int tid  = threadIdx.x;
  const int lane = tid & 63, wid = tid >> 6;
  const int wm   = wid >> 2, wn = wid & 3;
  const int lhi  = lane >> 4, llo = lane & 15;

  const char* Abase = (const char*)(Ap + (size_t)z * SEQ * SEQ) + (size_t)brow * 4096;
  const char* Bbase = (const char*)(Bp + (size_t)z * (size_t)DIM * SEQ) + (size_t)bcol * 4096;

  const int o1 = tid * 16;
  const int a1 = swz3(o1);
  const int sr1 = a1 >> 7, sk1 = a1 & 127;

  auto stA = [&](int buf, int u, int t) {
    gll16(Abase + (size_t)(u * 64 + sr1) * 4096 + t * 128 + sk1,
          LDS + buf * 16384 + u * 8192 + wid * 1024);
  };
  auto stB = [&](int buf, int u, int t) {
    gll16(Bbase + (size_t)(u * 64 + sr1) * 4096 + t * 128 + sk1,
          LDS + 32768 + buf * 24576 + u * 8192 + wid * 1024);
  };

  f32x4 acc[4][3];
  #pragma unroll
  for (int m = 0; m < 4; ++m)
    #pragma unroll
    for (int n = 0; n < 3; ++n)
      acc[m][n] = (f32x4)(0.0f);

  // prologue: tile0 (A 2 + B 3) + tile1 B (3)
  stA(0, 0, 0); stA(0, 1, 0);
  stB(0, 0, 0); stB(0, 1, 0); stB(0, 2, 0);
  stB(1, 0, 1); stB(1, 1, 1); stB(1, 2, 1);
  VMC(3);
  BAR();

  auto ITER = [&](int i, bool last) {
    short8 aR[2][2], bR[3][2];
    #pragma unroll
    for (int ph = 0; ph < 4; ++ph) {
      const int buf = ph >> 1;
      const int h   = ph & 1;
      // A reads: h-half (2 frags x 2 kh)
      #pragma unroll
      for (int fm = 0; fm < 2; ++fm)
        #pragma unroll
        for (int kh = 0; kh < 2; ++kh) {
          int o = (wm * 64 + h * 32 + fm * 16 + llo) * 128 + kh * 64 + lhi * 16;
          aR[fm][kh] = *(const short8*)(LDS + buf * 16384 + swz3(o));
        }
      // B reads: all 3 frags at the first phase of each buf
      if (h == 0) {
        #pragma unroll
        for (int fn = 0; fn < 3; ++fn)
          #pragma unroll
          for (int kh = 0; kh < 2; ++kh) {
            int o = (wn * 48 + fn * 16 + llo) * 128 + kh * 64 + lhi * 16;
            bR[fn][kh] = *(const short8*)(LDS + 32768 + buf * 24576 + swz3(o));
          }
      }
      if (ph == 0) { stA(1, 0, 2 * i + 1); stA(1, 1, 2 * i + 1); }
      else if (ph == 1) { if (!last) { stB(0, 0, 2*i+2); stB(0, 1, 2*i+2); stB(0, 2, 2*i+2); } }
      else if (ph == 2) { if (!last) { stA(0, 0, 2*i+2); stA(0, 1, 2*i+2); } }
      else              { if (!last) { stB(1, 0, 2*i+3); stB(1, 1, 2*i+3); stB(1, 2, 2*i+3); } }
      if (ph == 1) { if (last) { VMC(0); } else { VMC(3); } }
      if (ph == 3) { if (!last) { VMC(3); } }
      BAR();
      WAITL0();
      __builtin_amdgcn_sched_barrier(0);
      __builtin_amdgcn_s_setprio(1);
      #pragma unroll
      for (int kh = 0; kh < 2; ++kh)
        #pragma unroll
        for (int fm = 0; fm < 2; ++fm)
          #pragma unroll
          for (int fn = 0; fn < 3; ++fn)
            acc[h * 2 + fm][fn] = __builtin_amdgcn_mfma_f32_16x16x32_bf16(
                aR[fm][kh], bR[fn][kh], acc[h * 2 + fm][fn], 0, 0, 0);
      __builtin_amdgcn_s_setprio(0);
      BAR();
    }
  };

  for (int i = 0; i < NITER - 1; ++i) ITER(i, false);
  ITER(NITER - 1, true);

  float* C = Cf + (size_t)z * SEQ * DIM;
  const float* Q = qres + (size_t)z * SEQ * DIM;
  #pragma unroll
  for (int FM = 0; FM < 4; ++FM)
    #pragma unroll
    for (int r = 0; r < 4; ++r) {
      int rowg = brow + wm * 64 + FM * 16 + lhi * 4 + r;
      #pragma unroll
      for (int FN = 0; FN < 3; ++FN) {
        int colg = bcol + wn * 48 + FN * 16 + llo;
        C[(size_t)rowg * DIM + colg] = acc[FM][FN][r] + Q[(size_t)rowg * DIM + colg];
      }
    }
}

// ---------------------------------------------------------------------------
// Fallback PV GEMM (f32 weights + f32 v), single-buffer — only if ws too small.
// ---------------------------------------------------------------------------
__global__ __launch_bounds__(256)
void gemm_slow(const float* __restrict__ Wf, const float* __restrict__ Vf,
               const float* __restrict__ qres, float* __restrict__ Cf)
{
  __shared__ __align__(16) unsigned short AsL[128 * 64];
  __shared__ __align__(16) unsigned short BsL[128 * 32];

  const int tid  = threadIdx.x;
  const int z    = blockIdx.z;
  const int brow = blockIdx.y * 128;
  const int bcol = blockIdx.x * 128;
  const int lane = tid & 63;
  const int wid  = tid >> 6;
  const int wr   = (wid >> 1) * 64;
  const int wc   = (wid & 1) * 64;
  const int lhi  = lane >> 4;
  const int llo  = lane & 15;

  const float* AsrcF = Wf + (size_t)z * SEQ * SEQ + (size_t)brow * SEQ;
  const float* BsrcF = Vf + (size_t)z * SEQ * DIM;

  f32x4 acc[4][4];
  #pragma unroll
  for (int m = 0; m < 4; ++m)
    #pragma unroll
    for (int n = 0; n < 4; ++n)
      acc[m][n] = (f32x4)(0.0f);

  for (int k0 = 0; k0 < SEQ; k0 += 32) {
    #pragma unroll
    for (int i = 0; i < 4; ++i) {
      int ob = wid * 4096 + i * 1024;
      int a  = swz3(ob + lane * 16);
      gll16((const char*)AsrcF + (size_t)(a >> 7) * (SEQ * 4) + (size_t)k0 * 4 + (a & 127),
            (char*)AsL + ob);
    }
    {
      int n4 = (tid & 31) << 2;
      int kb = (tid >> 5) << 2;
      float4 r0 = *(const float4*)(BsrcF + (size_t)(k0 + kb + 0) * DIM + bcol + n4);
      float4 r1 = *(const float4*)(BsrcF + (size_t)(k0 + kb + 1) * DIM + bcol + n4);
      float4 r2 = *(const float4*)(BsrcF + (size_t)(k0 + kb + 2) * DIM + bcol + n4);
      float4 r3 = *(const float4*)(BsrcF + (size_t)(k0 + kb + 3) * DIM + bcol + n4);
      float a0[4] = {r0.x, r0.y, r0.z, r0.w};
      float a1[4] = {r1.x, r1.y, r1.z, r1.w};
      float a2[4] = {r2.x, r2.y, r2.z, r2.w};
      float a3[4] = {r3.x, r3.y, r3.z, r3.w};
      #pragma unroll
      for (int jj = 0; jj < 4; ++jj) {
        unsigned lo = (__float_as_uint(a0[jj]) >> 16) | (__float_as_uint(a1[jj]) & 0xFFFF0000u);
        unsigned hi = (__float_as_uint(a2[jj]) >> 16) | (__float_as_uint(a3[jj]) & 0xFFFF0000u);
        int ol = (n4 + jj) * 64 + kb * 2;
        *(uint2*)((char*)BsL + swz2(ol)) = make_uint2(lo, hi);
      }
    }
    __syncthreads();

    short8 af[4], bfr[4];
    #pragma unroll
    for (int m = 0; m < 4; ++m) {
      int row = wr + m * 16 + llo;
      int a0i = row * 128 + lhi * 32;
      f32x4 x = *(const f32x4*)((const char*)AsL + swz3(a0i));
      f32x4 y = *(const f32x4*)((const char*)AsL + swz3(a0i + 16));
      union { unsigned u[4]; short8 s; } r;
      r.u[0] = (__float_as_uint(x[0]) >> 16) | (__float_as_uint(x[1]) & 0xFFFF0000u);
      r.u[1] = (__float_as_uint(x[2]) >> 16) | (__float_as_uint(x[3]) & 0xFFFF0000u);
      r.u[2] = (__float_as_uint(y[0]) >> 16) | (__float_as_uint(y[1]) & 0xFFFF0000u);
      r.u[3] = (__float_as_uint(y[2]) >> 16) | (__float_as_uint(y[3]) & 0xFFFF0000u);
      af[m] = r.s;
    }
    #pragma unroll
    for (int n = 0; n < 4; ++n) {
      int a = (wc + n * 16 + llo) * 64 + lhi * 16;
      bfr[n] = *(const short8*)((const char*)BsL + swz2(a));
    }
    #pragma unroll
    for (int m = 0; m < 4; ++m)
      #pragma unroll
      for (int n = 0; n < 4; ++n)
        acc[m][n] = __builtin_amdgcn_mfma_f32_16x16x32_bf16(af[m], bfr[n], acc[m][n], 0, 0, 0);
    __syncthreads();
  }

  float* C = Cf + (size_t)z * SEQ * DIM;
  const float* Q = qres + (size_t)z * SEQ * DIM;
  #pragma unroll
  for (int m = 0; m < 4; ++m)
    #pragma unroll
    for (int r = 0; r < 4; ++r) {
      int rowg = brow + wr + m * 16 + lhi * 4 + r;
      #pragma unroll
      for (int n = 0; n < 4; ++n) {
        int colg = bcol + wc + n * 16 + llo;
        C[(size_t)rowg * DIM + colg] = acc[m][n][r] + Q[(size_t)rowg * DIM + colg];
      }
    }
}

// ---------------------------------------------------------------------------
// Fused prepack: q -> qb, k -> kb slot, v -> vb slot AND v^T -> vT.
// ---------------------------------------------------------------------------
__global__ __launch_bounds__(256)
void prepack_fused(const float* __restrict__ q, const float* __restrict__ k,
                   const float* __restrict__ v, unsigned short* __restrict__ qb,
                   unsigned short* __restrict__ wsl, unsigned short* __restrict__ vT,
                   int dovT)
{
  __shared__ unsigned short T[64][66];
  const int z  = blockIdx.z;
  const int r0 = blockIdx.y * 64, c0 = blockIdx.x * 64;
  const size_t mb = (size_t)z * SEQ * DIM;
  const int t16 = threadIdx.x & 15, trw = threadIdx.x >> 4;

  #pragma unroll
  for (int j = 0; j < 4; ++j) {
    int row = j * 16 + trw;
    size_t e = mb + (size_t)(r0 + row) * DIM + c0 + t16 * 4;
    float4 qv = *(const float4*)(q + e);
    float4 kv = *(const float4*)(k + e);
    float4 vv = *(const float4*)(v + e);
    ushort4 qo; qo.x = f2bf(qv.x); qo.y = f2bf(qv.y); qo.z = f2bf(qv.z); qo.w = f2bf(qv.w);
    ushort4 ko; ko.x = f2bf(kv.x); ko.y = f2bf(kv.y); ko.z = f2bf(kv.z); ko.w = f2bf(kv.w);
    ushort4 vo; vo.x = f2bf(vv.x); vo.y = f2bf(vv.y); vo.z = f2bf(vv.z); vo.w = f2bf(vv.w);
    *(ushort4*)(qb + e) = qo;
    size_t so = (size_t)(z * SEQ + r0 + row) * 4096 + 2048 + c0 + t16 * 4;
    *(ushort4*)(wsl + so) = ko;
    *(ushort4*)(wsl + so + DIM) = vo;
    *(unsigned*)&T[row][t16 * 4]     = (unsigned)vo.x | ((unsigned)vo.y << 16);
    *(unsigned*)&T[row][t16 * 4 + 2] = (unsigned)vo.z | ((unsigned)vo.w << 16);
  }
  __syncthreads();
  if (dovT) {
    const int tc = threadIdx.x & 63, tr2 = threadIdx.x >> 6;
    unsigned short* vTm = vT + (size_t)z * DIM * SEQ;
    #pragma unroll
    for (int j = 0; j < 16; ++j) {
      int orow = j * 4 + tr2;
      vTm[(size_t)(c0 + orow) * SEQ + r0 + tc] = T[tc][orow];
    }
  }
}

// [R][C] f32 -> [C][R] bf16 (W1 only)
__global__ __launch_bounds__(256)
void transpose_f32_bf16(const float* __restrict__ src, unsigned short* __restrict__ dst,
                        int R, int C)
{
  __shared__ unsigned short T[64][65];
  int r0 = blockIdx.y * 64, c0 = blockIdx.x * 64;
  int tr = threadIdx.x >> 6, tc = threadIdx.x & 63;
  #pragma unroll
  for (int j = 0; j < 16; ++j) {
    int row = j * 4 + tr;
    T[row][tc] = f2bf(src[(size_t)(r0 + row) * C + c0 + tc]);
  }
  __syncthreads();
  #pragma unroll
  for (int j = 0; j < 16; ++j) {
    int row = j * 4 + tr;
    dst[(size_t)(c0 + row) * R + r0 + tc] = T[tc][row];
  }
}

// lcol = sum of 8 scores row-block partials; g = b2 + 4 gate col-block partials
__global__ void finalize(const float* __restrict__ pl, const float* __restrict__ pg,
                         const float* __restrict__ b2, float* __restrict__ lcol,
                         float* __restrict__ g)
{
  int i = blockIdx.x * 256 + threadIdx.x;
  float l = 0.f;
  #pragma unroll
  for (int ch = 0; ch < 8; ++ch) l += pl[ch * 16384 + i];
  lcol[i] = l;
  g[i] = b2[0] + pg[i] + pg[16384 + i] + pg[2 * 16384 + i] + pg[3 * 16384 + i];
}

// Row pass: s = exp(x)/lcol; t = (s*(1-g) + g/S)/sqrt(768); row softmax.
template<bool FAST>
__global__ __launch_bounds__(256)
void rowpass(float* __restrict__ w, const float* __restrict__ lcol,
             const float* __restrict__ gg, unsigned short* __restrict__ wb)
{
  const size_t row = blockIdx.x;
  const int b = (int)(row >> 11);
  const unsigned short* p = (const unsigned short*)w + row * 4096;
  float* wrow = w + row * 2048;
  const int c0 = threadIdx.x * 8;
  const float* lc = lcol + (b << 11);
  const float* gb = gg + (b << 11);

  unsigned short xs[8];
  *(ushort4*)&xs[0] = *(const ushort4*)(p + c0);
  *(ushort4*)&xs[4] = *(const ushort4*)(p + c0 + 4);
  float ls[8], gs[8];
  *(float4*)&ls[0] = *(const float4*)(lc + c0);
  *(float4*)&ls[4] = *(const float4*)(lc + c0 + 4);
  *(float4*)&gs[0] = *(const float4*)(gb + c0);
  *(float4*)&gs[4] = *(const float4*)(gb + c0 + 4);

  float e[8];
  float psum = 0.f;
  #pragma unroll
  for (int j = 0; j < 8; ++j) {
    float s = __expf(bf2f(xs[j])) / ls[j];
    float t = (s * (1.f - gs[j]) + gs[j] * (1.f / 2048.f)) * 0.03608439182435161f;
    float ev = __expf(t);
    e[j] = ev;
    psum += ev;
  }
  #pragma unroll
  for (int off = 1; off < 64; off <<= 1) psum += __shfl_xor(psum, off);
  __shared__ float red[4];
  if ((threadIdx.x & 63) == 0) red[threadIdx.x >> 6] = psum;
  __syncthreads();
  float inv = 1.f / (red[0] + red[1] + red[2] + red[3]);
  float4 o0, o1;
  o0.x = e[0] * inv; o0.y = e[1] * inv; o0.z = e[2] * inv; o0.w = e[3] * inv;
  o1.x = e[4] * inv; o1.y = e[5] * inv; o1.z = e[6] * inv; o1.w = e[7] * inv;
  *(float4*)(wrow + c0) = o0;
  *(float4*)(wrow + c0 + 4) = o1;
  if constexpr (FAST) {
    ushort4 b0, b1v;
    b0.x = f2bf(o0.x); b0.y = f2bf(o0.y); b0.z = f2bf(o0.z); b0.w = f2bf(o0.w);
    b1v.x = f2bf(o1.x); b1v.y = f2bf(o1.y); b1v.z = f2bf(o1.z); b1v.w = f2bf(o1.w);
    *(ushort4*)(wb + row * 2048 + c0) = b0;
    *(ushort4*)(wb + row * 2048 + c0 + 4) = b1v;
  }
}

extern "C" void kernel_launch(void* const* d_in, const int* in_sizes, int n_in,
                              void* d_out, int out_size, void* d_ws, size_t ws_size,
                              hipStream_t stream)
{
  (void)in_sizes; (void)n_in; (void)out_size;
  const float* q  = (const float*)d_in[0];
  const float* k  = (const float*)d_in[1];
  const float* v  = (const float*)d_in[2];
  const float* W1 = (const float*)d_in[3];
  const float* b1 = (const float*)d_in[4];
  const float* W2 = (const float*)d_in[5];
  const float* b2 = (const float*)d_in[6];

  float* out0 = (float*)d_out;                       // [B,S,D] f32 (holds qb until PV)
  float* wbuf = out0 + (size_t)BATCH * SEQ * DIM;    // [B,S,S] f32 weights slots
  unsigned short* wsl = (unsigned short*)wbuf;       // slot view (lower: scores, upper: kb/vb)
  unsigned short* qb  = (unsigned short*)out0;

  float* g    = (float*)d_ws;                        // 16384
  float* lcol = g + 16384;                           // 16384
  float* pg   = lcol + 16384;                        // 65536 (4 used)
  float* pl   = pg + 65536;                          // 262144 (8*16384 used)
  unsigned short* W1T = (unsigned short*)(pl + 262144);            // 393216 ushorts
  unsigned short* vT  = (unsigned short*)((char*)d_ws + 2228224);  // 12.58M ushorts
  unsigned short* wb  = vT + (size_t)12582912;                     // 33.55M ushorts
  const bool fast = ws_size >= 94502912ull;

  prepack_fused<<<dim3(12, 32, 8), 256, 0, stream>>>(q, k, v, qb, wsl, vT, fast ? 1 : 0);
  transpose_f32_bf16<<<dim3(8, 12, 1), 256, 0, stream>>>(W1, W1T, 768, 512);

  // gate: 8-phase 256x128, grid 256 (1 exact round) -> pg[4][16384]
  gemm_gate8<<<256, 512, 0, stream>>>(wsl + 2816, W1T, b1, W2, pg);
  // scores: 8-phase 256^2 -> bf16 into weight-row slots + column exp-sum partials
  gemm8<1><<<512, 512, 0, stream>>>(qb, wsl, nullptr, wbuf, nullptr, nullptr, nullptr, pl);

  finalize<<<64, 256, 0, stream>>>(pl, pg, b2, lcol, g);

  if (fast) {
    rowpass<true><<<16384, 256, 0, stream>>>(wbuf, lcol, g, wb);
    // PV: 4-phase 128x192, grid 512, 2 blocks/CU
    gemm_pv<<<512, 512, 0, stream>>>(wb, vT, q, out0);
  } else {
    rowpass<false><<<16384, 256, 0, stream>>>(wbuf, lcol, g, nullptr);
    gemm_slow<<<dim3(6, 16, 8), 256, 0, stream>>>(wbuf, v, q, out0);
  }
}

// Round 8
// 250.289 us; speedup vs baseline: 1.8153x; 1.0125x over previous
//
#include <hip/hip_runtime.h>

#define BATCH 8
#define SEQ   2048
#define DIM   768
#define HID   512

typedef __attribute__((ext_vector_type(8))) short  short8;
typedef __attribute__((ext_vector_type(4))) float  f32x4;

#define BAR()    asm volatile("s_barrier" ::: "memory")
#define WAITL0() asm volatile("s_waitcnt lgkmcnt(0)" ::: "memory")
#define VMC(n)   asm volatile("s_waitcnt vmcnt(" #n ")" ::: "memory")

__device__ __forceinline__ unsigned short f2bf(float f) {
  union { float f; unsigned u; } x; x.f = f;
  return (unsigned short)((x.u + 0x7FFFu + ((x.u >> 16) & 1u)) >> 16);
}
__device__ __forceinline__ float bf2f(unsigned short u) {
  union { unsigned u; float f; } x; x.u = ((unsigned)u) << 16;
  return x.f;
}
__device__ __forceinline__ void gll16(const void* g, void* l) {
  __builtin_amdgcn_global_load_lds(
      (const __attribute__((address_space(1))) void*)g,
      (__attribute__((address_space(3))) void*)l, 16, 0, 0);
}
// XOR swizzles (involutions; keep bits 0-3 so 16B chunks stay contiguous)
__device__ __forceinline__ int swz2(int o) { return o ^ (((o >> 8) & 7) << 4); }  // 64B rows
__device__ __forceinline__ int swz3(int o) { return o ^ (((o >> 7) & 7) << 4); }  // 128B rows

// ---------------------------------------------------------------------------
// 8-phase 256x256 BK=64 bf16 GEMM (scores). Proven rounds 5-7. Grid 512.
// ---------------------------------------------------------------------------
template<int VAR>
__global__ __launch_bounds__(512, 2)
void gemm8(const unsigned short* __restrict__ Ap, const unsigned short* __restrict__ Bp,
           const float* __restrict__ qres, float* __restrict__ Cf,
           const float* __restrict__ bias, const float* __restrict__ W2,
           float* __restrict__ pg, float* __restrict__ pl)
{
  constexpr int K     = (VAR == 2) ? SEQ : DIM;
  constexpr int NT    = K / 64;
  constexpr int NITER = NT / 2;
  constexpr int APB   = (VAR == 0) ? 8192 : (VAR == 1 ? 1536 : 4096);
  constexpr int BPB   = (VAR == 0) ? 1536 : (VAR == 1 ? 8192 : 4096);
  constexpr int GX    = (VAR == 0) ? 2 : (VAR == 1 ? 8 : 3);
  constexpr int GY    = (VAR == 0) ? 64 : 8;
  constexpr int NB    = (VAR == 0) ? 1 : BATCH;
  constexpr int NWG   = GX * GY * NB;

  __shared__ __align__(16) unsigned char LDS[131072];   // A: 2x32K @0, B: 2x32K @64K

  int wg = ((blockIdx.x & 7) * (NWG >> 3)) + ((int)blockIdx.x >> 3);
  const int z  = wg / (GX * GY);
  const int r2 = wg % (GX * GY);
  const int by = r2 / GX;
  const int bx = r2 % GX;
  const int brow = by * 256, bcol = bx * 256;

  const int tid  = threadIdx.x;
  const int lane = tid & 63, wid = tid >> 6;
  const int wm   = wid >> 2, wn = wid & 3;
  const int lhi  = lane >> 4, llo = lane & 15;

  const char* Abase;
  const char* Bbase;
  if constexpr (VAR == 0) {
    Abase = (const char*)Ap + (size_t)brow * APB;
    Bbase = (const char*)Bp + (size_t)bcol * BPB;
  } else if constexpr (VAR == 1) {
    Abase = (const char*)(Ap + (size_t)z * SEQ * DIM) + (size_t)brow * APB;
    Bbase = (const char*)(Bp + (size_t)z * SEQ * 4096 + 2048) + (size_t)bcol * BPB;
  } else {
    Abase = (const char*)(Ap + (size_t)z * SEQ * SEQ) + (size_t)brow * APB;
    Bbase = (const char*)(Bp + (size_t)z * (size_t)DIM * SEQ) + (size_t)bcol * BPB;
  }

  int sr[2], sk[2];
  #pragma unroll
  for (int c = 0; c < 2; ++c) {
    int o = wid * 2048 + c * 1024 + lane * 16;
    int a = swz3(o);
    sr[c] = a >> 7; sk[c] = a & 127;
  }
  auto stA = [&](int buf, int hh, int t) {
    #pragma unroll
    for (int c = 0; c < 2; ++c)
      gll16(Abase + (size_t)(hh * 128 + sr[c]) * APB + t * 128 + sk[c],
            LDS + buf * 32768 + hh * 16384 + wid * 2048 + c * 1024);
  };
  auto stB = [&](int buf, int hh, int t) {
    #pragma unroll
    for (int c = 0; c < 2; ++c)
      gll16(Bbase + (size_t)(hh * 128 + sr[c]) * BPB + t * 128 + sk[c],
            LDS + 65536 + buf * 32768 + hh * 16384 + wid * 2048 + c * 1024);
  };

  f32x4 acc[8][4];
  #pragma unroll
  for (int m = 0; m < 8; ++m)
    #pragma unroll
    for (int n = 0; n < 4; ++n)
      acc[m][n] = (f32x4)(0.0f);

  stA(0, 0, 0); stA(0, 1, 0); stB(0, 0, 0); stB(0, 1, 0);
  stB(1, 0, 1); stB(1, 1, 1);
  VMC(4);
  BAR();

  auto ITER = [&](int i, bool last) {
    #pragma unroll
    for (int kk = 0; kk < 2; ++kk) {
      const int buf = kk;
      short8 aR[4][2], b0R[2][2], b1R[2][2];
      #pragma unroll
      for (int ph = 0; ph < 4; ++ph) {
        const int h  = ph >> 1;
        const int nh = (ph == 1 || ph == 2) ? 1 : 0;
        if (ph == 0 || ph == 2) {
          #pragma unroll
          for (int fm = 0; fm < 4; ++fm)
            #pragma unroll
            for (int kh = 0; kh < 2; ++kh) {
              int o = (wm * 128 + h * 64 + fm * 16 + llo) * 128 + kh * 64 + lhi * 16;
              aR[fm][kh] = *(const short8*)(LDS + buf * 32768 + swz3(o));
            }
        }
        if (ph == 0) {
          #pragma unroll
          for (int fn = 0; fn < 2; ++fn)
            #pragma unroll
            for (int kh = 0; kh < 2; ++kh) {
              int o = (wn * 64 + fn * 16 + llo) * 128 + kh * 64 + lhi * 16;
              b0R[fn][kh] = *(const short8*)(LDS + 65536 + buf * 32768 + swz3(o));
            }
        }
        if (ph == 1) {
          #pragma unroll
          for (int fn = 0; fn < 2; ++fn)
            #pragma unroll
            for (int kh = 0; kh < 2; ++kh) {
              int o = (wn * 64 + 32 + fn * 16 + llo) * 128 + kh * 64 + lhi * 16;
              b1R[fn][kh] = *(const short8*)(LDS + 65536 + buf * 32768 + swz3(o));
            }
        }
        const int P = kk * 4 + ph;
        if      (P == 0) stA(1, 0, 2 * i + 1);
        else if (P == 1) stA(1, 1, 2 * i + 1);
        else if (P == 2) { if (!last) stB(0, 0, 2 * i + 2); }
        else if (P == 3) { if (!last) stB(0, 1, 2 * i + 2); }
        else if (P == 4) { if (!last) stA(0, 0, 2 * i + 2); }
        else if (P == 5) { if (!last) stA(0, 1, 2 * i + 2); }
        else if (P == 6) { if (!last) stB(1, 0, 2 * i + 3); }
        else if (P == 7) { if (!last) stB(1, 1, 2 * i + 3); }
        if (P == 3) { if (last) { VMC(0); } else { VMC(4); } }
        if (P == 7) { if (!last) { VMC(4); } }
        BAR();
        WAITL0();
        __builtin_amdgcn_sched_barrier(0);
        __builtin_amdgcn_s_setprio(1);
        #pragma unroll
        for (int kh = 0; kh < 2; ++kh)
          #pragma unroll
          for (int fm = 0; fm < 4; ++fm)
            #pragma unroll
            for (int fn = 0; fn < 2; ++fn)
              acc[h * 4 + fm][nh * 2 + fn] = __builtin_amdgcn_mfma_f32_16x16x32_bf16(
                  aR[fm][kh], nh ? b1R[fn][kh] : b0R[fn][kh],
                  acc[h * 4 + fm][nh * 2 + fn], 0, 0, 0);
        __builtin_amdgcn_s_setprio(0);
        BAR();
      }
    }
  };

  for (int i = 0; i < NITER - 1; ++i) ITER(i, false);
  ITER(NITER - 1, true);

  if constexpr (VAR == 1) {
    const float rs = 0.02209708691207961f;  // 1/sqrt(2048)
    unsigned short* C16 = reinterpret_cast<unsigned short*>(Cf);
    float cs[4] = {0.f, 0.f, 0.f, 0.f};
    #pragma unroll
    for (int FM = 0; FM < 8; ++FM)
      #pragma unroll
      for (int r = 0; r < 4; ++r) {
        size_t R = (size_t)z * SEQ + (brow + wm * 128 + FM * 16 + lhi * 4 + r);
        #pragma unroll
        for (int FN = 0; FN < 4; ++FN) {
          int col = bcol + wn * 64 + FN * 16 + llo;
          unsigned short us = f2bf(acc[FM][FN][r] * rs);
          C16[R * 4096 + col] = us;
          cs[FN] += __expf(bf2f(us));
        }
      }
    float* cp = (float*)LDS;
    #pragma unroll
    for (int FN = 0; FN < 4; ++FN) {
      cs[FN] += __shfl_xor(cs[FN], 16);
      cs[FN] += __shfl_xor(cs[FN], 32);
      if (lhi == 0) cp[wm * 256 + wn * 64 + FN * 16 + llo] = cs[FN];
    }
    __syncthreads();
    if (tid < 256)
      pl[(size_t)by * 16384 + z * 2048 + bcol + tid] = cp[tid] + cp[256 + tid];
  }
}

// ---------------------------------------------------------------------------
// Gate GEMM, 8-phase 256x128 BK=64. Grid 256 = 1 exact round. Proven round 7.
// ---------------------------------------------------------------------------
__global__ __launch_bounds__(512, 2)
void gemm_gate8(const unsigned short* __restrict__ Ap, const unsigned short* __restrict__ Bp,
                const float* __restrict__ bias, const float* __restrict__ W2,
                float* __restrict__ pg)
{
  constexpr int NITER = 6;   // K=768 -> 12 BK=64 tiles
  __shared__ __align__(16) unsigned char LDS[98304];  // A 2x32K @0, B 2x16K @65536

  int wg = ((blockIdx.x & 7) * 32) + ((int)blockIdx.x >> 3);
  const int by = wg >> 2, bx = wg & 3;
  const int brow = by * 256, bcol = bx * 128;

  const int tid  = threadIdx.x;
  const int lane = tid & 63, wid = tid >> 6;
  const int wm   = wid >> 2, wn = wid & 3;
  const int lhi  = lane >> 4, llo = lane & 15;

  const char* Abase = (const char*)Ap + (size_t)brow * 8192;
  const char* Bbase = (const char*)Bp + (size_t)bcol * 1536;

  int srA[2], skA[2];
  #pragma unroll
  for (int c = 0; c < 2; ++c) {
    int o = wid * 2048 + c * 1024 + lane * 16;
    int a = swz3(o);
    srA[c] = a >> 7; skA[c] = a & 127;
  }
  const int o1 = tid * 16;
  const int a1 = swz3(o1);
  const int sr1 = a1 >> 7, sk1 = a1 & 127;

  auto stA = [&](int buf, int hh, int t) {
    #pragma unroll
    for (int c = 0; c < 2; ++c)
      gll16(Abase + (size_t)(hh * 128 + srA[c]) * 8192 + t * 128 + skA[c],
            LDS + buf * 32768 + hh * 16384 + wid * 2048 + c * 1024);
  };
  auto stB = [&](int buf, int hh, int t) {
    gll16(Bbase + (size_t)(hh * 64 + sr1) * 1536 + t * 128 + sk1,
          LDS + 65536 + buf * 16384 + hh * 8192 + wid * 1024);
  };

  f32x4 acc[8][2];
  #pragma unroll
  for (int m = 0; m < 8; ++m)
    #pragma unroll
    for (int n = 0; n < 2; ++n)
      acc[m][n] = (f32x4)(0.0f);

  stA(0, 0, 0); stA(0, 1, 0); stB(0, 0, 0); stB(0, 1, 0);
  stB(1, 0, 1); stB(1, 1, 1);
  VMC(2);
  BAR();

  auto ITER = [&](int i, bool last) {
    #pragma unroll
    for (int kk = 0; kk < 2; ++kk) {
      const int buf = kk;
      short8 aR[4][2], b0R[2], b1R[2];
      #pragma unroll
      for (int ph = 0; ph < 4; ++ph) {
        const int h  = ph >> 1;
        const int nh = (ph == 1 || ph == 2) ? 1 : 0;
        if (ph == 0 || ph == 2) {
          #pragma unroll
          for (int fm = 0; fm < 4; ++fm)
            #pragma unroll
            for (int kh = 0; kh < 2; ++kh) {
              int o = (wm * 128 + h * 64 + fm * 16 + llo) * 128 + kh * 64 + lhi * 16;
              aR[fm][kh] = *(const short8*)(LDS + buf * 32768 + swz3(o));
            }
        }
        if (ph == 0) {
          #pragma unroll
          for (int kh = 0; kh < 2; ++kh) {
            int o = (wn * 32 + llo) * 128 + kh * 64 + lhi * 16;
            b0R[kh] = *(const short8*)(LDS + 65536 + buf * 16384 + swz3(o));
          }
        }
        if (ph == 1) {
          #pragma unroll
          for (int kh = 0; kh < 2; ++kh) {
            int o = (wn * 32 + 16 + llo) * 128 + kh * 64 + lhi * 16;
            b1R[kh] = *(const short8*)(LDS + 65536 + buf * 16384 + swz3(o));
          }
        }
        const int P = kk * 4 + ph;
        if      (P == 0) stA(1, 0, 2 * i + 1);
        else if (P == 1) stA(1, 1, 2 * i + 1);
        else if (P == 2) { if (!last) stB(0, 0, 2 * i + 2); }
        else if (P == 3) { if (!last) stB(0, 1, 2 * i + 2); }
        else if (P == 4) { if (!last) stA(0, 0, 2 * i + 2); }
        else if (P == 5) { if (!last) stA(0, 1, 2 * i + 2); }
        else if (P == 6) { if (!last) stB(1, 0, 2 * i + 3); }
        else if (P == 7) { if (!last) stB(1, 1, 2 * i + 3); }
        if (P == 3) { if (last) { VMC(0); } else { VMC(2); } }
        if (P == 7) { if (!last) { VMC(2); } }
        BAR();
        WAITL0();
        __builtin_amdgcn_sched_barrier(0);
        __builtin_amdgcn_s_setprio(1);
        #pragma unroll
        for (int kh = 0; kh < 2; ++kh)
          #pragma unroll
          for (int fm = 0; fm < 4; ++fm)
            acc[h * 4 + fm][nh] = __builtin_amdgcn_mfma_f32_16x16x32_bf16(
                aR[fm][kh], nh ? b1R[kh] : b0R[kh], acc[h * 4 + fm][nh], 0, 0, 0);
        __builtin_amdgcn_s_setprio(0);
        BAR();
      }
    }
  };

  for (int i = 0; i < NITER - 1; ++i) ITER(i, false);
  ITER(NITER - 1, true);

  float* gredF = (float*)LDS;   // [256][4]
  float b1v[2], w2v[2];
  #pragma unroll
  for (int FN = 0; FN < 2; ++FN) {
    int colg = bcol + wn * 32 + FN * 16 + llo;
    b1v[FN] = bias[colg]; w2v[FN] = W2[colg];
  }
  #pragma unroll
  for (int FM = 0; FM < 8; ++FM)
    #pragma unroll
    for (int r = 0; r < 4; ++r) {
      float part = tanhf(acc[FM][0][r] + b1v[0]) * w2v[0]
                 + tanhf(acc[FM][1][r] + b1v[1]) * w2v[1];
      part += __shfl_xor(part, 1);
      part += __shfl_xor(part, 2);
      part += __shfl_xor(part, 4);
      part += __shfl_xor(part, 8);
      if (llo == 0) gredF[(wm * 128 + FM * 16 + lhi * 4 + r) * 4 + wn] = part;
    }
  __syncthreads();
  if (tid < 256)
    pg[(size_t)bx * 16384 + brow + tid] =
        gredF[tid * 4 + 0] + gredF[tid * 4 + 1] + gredF[tid * 4 + 2] + gredF[tid * 4 + 3];
}

// ---------------------------------------------------------------------------
// PV GEMM, 4-phase 128x192 BK=64, LDS 80K -> 2 blocks/CU. Proven round 7.
// ---------------------------------------------------------------------------
__global__ __launch_bounds__(512, 4)
void gemm_pv(const unsigned short* __restrict__ Ap, const unsigned short* __restrict__ Bp,
             const float* __restrict__ qres, float* __restrict__ Cf)
{
  constexpr int NITER = 16;  // K=2048 -> 32 BK=64 tiles
  __shared__ __align__(16) unsigned char LDS[81920];  // A 2x16K @0, B 2x24K @32768

  int wg = ((blockIdx.x & 7) * 64) + ((int)blockIdx.x >> 3);
  const int z  = wg >> 6;
  const int r2 = wg & 63;
  const int by = r2 >> 2, bx = r2 & 3;
  const int brow = by * 128, bcol = bx * 192;

  const int tid  = threadIdx.x;
  const int lane = tid & 63, wid = tid >> 6;
  const int wm   = wid >> 2, wn = wid & 3;
  const int lhi  = lane >> 4, llo = lane & 15;

  const char* Abase = (const char*)(Ap + (size_t)z * SEQ * SEQ) + (size_t)brow * 4096;
  const char* Bbase = (const char*)(Bp + (size_t)z * (size_t)DIM * SEQ) + (size_t)bcol * 4096;

  const int o1 = tid * 16;
  const int a1 = swz3(o1);
  const int sr1 = a1 >> 7, sk1 = a1 & 127;

  auto stA = [&](int buf, int u, int t) {
    gll16(Abase + (size_t)(u * 64 + sr1) * 4096 + t * 128 + sk1,
          LDS + buf * 16384 + u * 8192 + wid * 1024);
  };
  auto stB = [&](int buf, int u, int t) {
    gll16(Bbase + (size_t)(u * 64 + sr1) * 4096 + t * 128 + sk1,
          LDS + 32768 + buf * 24576 + u * 8192 + wid * 1024);
  };

  f32x4 acc[4][3];
  #pragma unroll
  for (int m = 0; m < 4; ++m)
    #pragma unroll
    for (int n = 0; n < 3; ++n)
      acc[m][n] = (f32x4)(0.0f);

  stA(0, 0, 0); stA(0, 1, 0);
  stB(0, 0, 0); stB(0, 1, 0); stB(0, 2, 0);
  stB(1, 0, 1); stB(1, 1, 1); stB(1, 2, 1);
  VMC(3);
  BAR();

  auto ITER = [&](int i, bool last) {
    short8 aR[2][2], bR[3][2];
    #pragma unroll
    for (int ph = 0; ph < 4; ++ph) {
      const int buf = ph >> 1;
      const int h   = ph & 1;
      #pragma unroll
      for (int fm = 0; fm < 2; ++fm)
        #pragma unroll
        for (int kh = 0; kh < 2; ++kh) {
          int o = (wm * 64 + h * 32 + fm * 16 + llo) * 128 + kh * 64 + lhi * 16;
          aR[fm][kh] = *(const short8*)(LDS + buf * 16384 + swz3(o));
        }
      if (h == 0) {
        #pragma unroll
        for (int fn = 0; fn < 3; ++fn)
          #pragma unroll
          for (int kh = 0; kh < 2; ++kh) {
            int o = (wn * 48 + fn * 16 + llo) * 128 + kh * 64 + lhi * 16;
            bR[fn][kh] = *(const short8*)(LDS + 32768 + buf * 24576 + swz3(o));
          }
      }
      if (ph == 0) { stA(1, 0, 2 * i + 1); stA(1, 1, 2 * i + 1); }
      else if (ph == 1) { if (!last) { stB(0, 0, 2*i+2); stB(0, 1, 2*i+2); stB(0, 2, 2*i+2); } }
      else if (ph == 2) { if (!last) { stA(0, 0, 2*i+2); stA(0, 1, 2*i+2); } }
      else              { if (!last) { stB(1, 0, 2*i+3); stB(1, 1, 2*i+3); stB(1, 2, 2*i+3); } }
      if (ph == 1) { if (last) { VMC(0); } else { VMC(3); } }
      if (ph == 3) { if (!last) { VMC(3); } }
      BAR();
      WAITL0();
      __builtin_amdgcn_sched_barrier(0);
      __builtin_amdgcn_s_setprio(1);
      #pragma unroll
      for (int kh = 0; kh < 2; ++kh)
        #pragma unroll
        for (int fm = 0; fm < 2; ++fm)
          #pragma unroll
          for (int fn = 0; fn < 3; ++fn)
            acc[h * 2 + fm][fn] = __builtin_amdgcn_mfma_f32_16x16x32_bf16(
                aR[fm][kh], bR[fn][kh], acc[h * 2 + fm][fn], 0, 0, 0);
      __builtin_amdgcn_s_setprio(0);
      BAR();
    }
  };

  for (int i = 0; i < NITER - 1; ++i) ITER(i, false);
  ITER(NITER - 1, true);

  float* C = Cf + (size_t)z * SEQ * DIM;
  const float* Q = qres + (size_t)z * SEQ * DIM;
  #pragma unroll
  for (int FM = 0; FM < 4; ++FM)
    #pragma unroll
    for (int r = 0; r < 4; ++r) {
      int rowg = brow + wm * 64 + FM * 16 + lhi * 4 + r;
      #pragma unroll
      for (int FN = 0; FN < 3; ++FN) {
        int colg = bcol + wn * 48 + FN * 16 + llo;
        C[(size_t)rowg * DIM + colg] = acc[FM][FN][r] + Q[(size_t)rowg * DIM + colg];
      }
    }
}

// ---------------------------------------------------------------------------
// Fallback PV GEMM (f32 weights + f32 v), single-buffer — only if ws too small.
// ---------------------------------------------------------------------------
__global__ __launch_bounds__(256)
void gemm_slow(const float* __restrict__ Wf, const float* __restrict__ Vf,
               const float* __restrict__ qres, float* __restrict__ Cf)
{
  __shared__ __align__(16) unsigned short AsL[128 * 64];
  __shared__ __align__(16) unsigned short BsL[128 * 32];

  const int tid  = threadIdx.x;
  const int z    = blockIdx.z;
  const int brow = blockIdx.y * 128;
  const int bcol = blockIdx.x * 128;
  const int lane = tid & 63;
  const int wid  = tid >> 6;
  const int wr   = (wid >> 1) * 64;
  const int wc   = (wid & 1) * 64;
  const int lhi  = lane >> 4;
  const int llo  = lane & 15;

  const float* AsrcF = Wf + (size_t)z * SEQ * SEQ + (size_t)brow * SEQ;
  const float* BsrcF = Vf + (size_t)z * SEQ * DIM;

  f32x4 acc[4][4];
  #pragma unroll
  for (int m = 0; m < 4; ++m)
    #pragma unroll
    for (int n = 0; n < 4; ++n)
      acc[m][n] = (f32x4)(0.0f);

  for (int k0 = 0; k0 < SEQ; k0 += 32) {
    #pragma unroll
    for (int i = 0; i < 4; ++i) {
      int ob = wid * 4096 + i * 1024;
      int a  = swz3(ob + lane * 16);
      gll16((const char*)AsrcF + (size_t)(a >> 7) * (SEQ * 4) + (size_t)k0 * 4 + (a & 127),
            (char*)AsL + ob);
    }
    {
      int n4 = (tid & 31) << 2;
      int kb = (tid >> 5) << 2;
      float4 r0 = *(const float4*)(BsrcF + (size_t)(k0 + kb + 0) * DIM + bcol + n4);
      float4 r1 = *(const float4*)(BsrcF + (size_t)(k0 + kb + 1) * DIM + bcol + n4);
      float4 r2 = *(const float4*)(BsrcF + (size_t)(k0 + kb + 2) * DIM + bcol + n4);
      float4 r3 = *(const float4*)(BsrcF + (size_t)(k0 + kb + 3) * DIM + bcol + n4);
      float a0[4] = {r0.x, r0.y, r0.z, r0.w};
      float a1[4] = {r1.x, r1.y, r1.z, r1.w};
      float a2[4] = {r2.x, r2.y, r2.z, r2.w};
      float a3[4] = {r3.x, r3.y, r3.z, r3.w};
      #pragma unroll
      for (int jj = 0; jj < 4; ++jj) {
        unsigned lo = (__float_as_uint(a0[jj]) >> 16) | (__float_as_uint(a1[jj]) & 0xFFFF0000u);
        unsigned hi = (__float_as_uint(a2[jj]) >> 16) | (__float_as_uint(a3[jj]) & 0xFFFF0000u);
        int ol = (n4 + jj) * 64 + kb * 2;
        *(uint2*)((char*)BsL + swz2(ol)) = make_uint2(lo, hi);
      }
    }
    __syncthreads();

    short8 af[4], bfr[4];
    #pragma unroll
    for (int m = 0; m < 4; ++m) {
      int row = wr + m * 16 + llo;
      int a0i = row * 128 + lhi * 32;
      f32x4 x = *(const f32x4*)((const char*)AsL + swz3(a0i));
      f32x4 y = *(const f32x4*)((const char*)AsL + swz3(a0i + 16));
      union { unsigned u[4]; short8 s; } r;
      r.u[0] = (__float_as_uint(x[0]) >> 16) | (__float_as_uint(x[1]) & 0xFFFF0000u);
      r.u[1] = (__float_as_uint(x[2]) >> 16) | (__float_as_uint(x[3]) & 0xFFFF0000u);
      r.u[2] = (__float_as_uint(y[0]) >> 16) | (__float_as_uint(y[1]) & 0xFFFF0000u);
      r.u[3] = (__float_as_uint(y[2]) >> 16) | (__float_as_uint(y[3]) & 0xFFFF0000u);
      af[m] = r.s;
    }
    #pragma unroll
    for (int n = 0; n < 4; ++n) {
      int a = (wc + n * 16 + llo) * 64 + lhi * 16;
      bfr[n] = *(const short8*)((const char*)BsL + swz2(a));
    }
    #pragma unroll
    for (int m = 0; m < 4; ++m)
      #pragma unroll
      for (int n = 0; n < 4; ++n)
        acc[m][n] = __builtin_amdgcn_mfma_f32_16x16x32_bf16(af[m], bfr[n], acc[m][n], 0, 0, 0);
    __syncthreads();
  }

  float* C = Cf + (size_t)z * SEQ * DIM;
  const float* Q = qres + (size_t)z * SEQ * DIM;
  #pragma unroll
  for (int m = 0; m < 4; ++m)
    #pragma unroll
    for (int r = 0; r < 4; ++r) {
      int rowg = brow + wr + m * 16 + lhi * 4 + r;
      #pragma unroll
      for (int n = 0; n < 4; ++n) {
        int colg = bcol + wc + n * 16 + llo;
        C[(size_t)rowg * DIM + colg] = acc[m][n][r] + Q[(size_t)rowg * DIM + colg];
      }
    }
}

// ---------------------------------------------------------------------------
// Fused prepack + W1 transpose (1D grid: 3072 prepack blocks + 96 W1T blocks).
// ---------------------------------------------------------------------------
__global__ __launch_bounds__(256)
void prepack_all(const float* __restrict__ q, const float* __restrict__ k,
                 const float* __restrict__ v, unsigned short* __restrict__ qb,
                 unsigned short* __restrict__ wsl, unsigned short* __restrict__ vT,
                 const float* __restrict__ W1, unsigned short* __restrict__ W1T,
                 int dovT)
{
  __shared__ unsigned short T[64][66];
  const int bid = blockIdx.x;
  if (bid < 3072) {
    const int bx = bid % 12, byy = (bid / 12) % 32, z = bid / 384;
    const int r0 = byy * 64, c0 = bx * 64;
    const size_t mb = (size_t)z * SEQ * DIM;
    const int t16 = threadIdx.x & 15, trw = threadIdx.x >> 4;

    #pragma unroll
    for (int j = 0; j < 4; ++j) {
      int row = j * 16 + trw;
      size_t e = mb + (size_t)(r0 + row) * DIM + c0 + t16 * 4;
      float4 qv = *(const float4*)(q + e);
      float4 kv = *(const float4*)(k + e);
      float4 vv = *(const float4*)(v + e);
      ushort4 qo; qo.x = f2bf(qv.x); qo.y = f2bf(qv.y); qo.z = f2bf(qv.z); qo.w = f2bf(qv.w);
      ushort4 ko; ko.x = f2bf(kv.x); ko.y = f2bf(kv.y); ko.z = f2bf(kv.z); ko.w = f2bf(kv.w);
      ushort4 vo; vo.x = f2bf(vv.x); vo.y = f2bf(vv.y); vo.z = f2bf(vv.z); vo.w = f2bf(vv.w);
      *(ushort4*)(qb + e) = qo;
      size_t so = (size_t)(z * SEQ + r0 + row) * 4096 + 2048 + c0 + t16 * 4;
      *(ushort4*)(wsl + so) = ko;
      *(ushort4*)(wsl + so + DIM) = vo;
      *(unsigned*)&T[row][t16 * 4]     = (unsigned)vo.x | ((unsigned)vo.y << 16);
      *(unsigned*)&T[row][t16 * 4 + 2] = (unsigned)vo.z | ((unsigned)vo.w << 16);
    }
    __syncthreads();
    if (dovT) {
      const int tc = threadIdx.x & 63, tr2 = threadIdx.x >> 6;
      unsigned short* vTm = vT + (size_t)z * DIM * SEQ;
      #pragma unroll
      for (int j = 0; j < 16; ++j) {
        int orow = j * 4 + tr2;
        vTm[(size_t)(c0 + orow) * SEQ + r0 + tc] = T[tc][orow];
      }
    }
  } else {
    // W1 [768x512] -> W1T [512x768]
    const int idx = bid - 3072;
    const int c0 = (idx & 7) * 64, r0 = (idx >> 3) * 64;
    const int tr = threadIdx.x >> 6, tc = threadIdx.x & 63;
    #pragma unroll
    for (int j = 0; j < 16; ++j) {
      int row = j * 4 + tr;
      T[row][tc] = f2bf(W1[(size_t)(r0 + row) * HID + c0 + tc]);
    }
    __syncthreads();
    #pragma unroll
    for (int j = 0; j < 16; ++j) {
      int row = j * 4 + tr;
      W1T[(size_t)(c0 + row) * DIM + r0 + tc] = T[tc][row];
    }
  }
}

// lcol = sum of 8 scores row-block partials; g = b2 + 4 gate col-block partials
__global__ void finalize(const float* __restrict__ pl, const float* __restrict__ pg,
                         const float* __restrict__ b2, float* __restrict__ lcol,
                         float* __restrict__ g)
{
  int i = blockIdx.x * 256 + threadIdx.x;
  float l = 0.f;
  #pragma unroll
  for (int ch = 0; ch < 8; ++ch) l += pl[ch * 16384 + i];
  lcol[i] = l;
  g[i] = b2[0] + pg[i] + pg[16384 + i] + pg[2 * 16384 + i] + pg[3 * 16384 + i];
}

// ---------------------------------------------------------------------------
// Row pass, wave-per-row: 8 waves/block, each wave owns one full 2048-col row.
// No LDS, no __syncthreads; row-softmax sum via 6-step shuffle. In-place safe
// (stores data-depend on this wave's loads; waves own disjoint rows).
// ---------------------------------------------------------------------------
__global__ __launch_bounds__(512)
void rowpass2(float* __restrict__ w, const float* __restrict__ lcol,
              const float* __restrict__ gg, unsigned short* __restrict__ wb)
{
  const int wave = threadIdx.x >> 6;
  const int lane = threadIdx.x & 63;
  const size_t row = (size_t)blockIdx.x * 8 + wave;
  const int b = (int)(row >> 11);
  const unsigned short* p = (const unsigned short*)w + row * 4096;
  float* wrow = w + row * 2048;
  unsigned short* wbrow = wb + row * 2048;
  const float* lc = lcol + (b << 11);
  const float* gb = gg + (b << 11);

  float ev[4][8];
  float psum = 0.f;
  #pragma unroll
  for (int j = 0; j < 4; ++j) {
    const int c0 = j * 512 + lane * 8;
    unsigned short xs[8];
    *(ushort4*)&xs[0] = *(const ushort4*)(p + c0);
    *(ushort4*)&xs[4] = *(const ushort4*)(p + c0 + 4);
    float ls[8], gs[8];
    *(float4*)&ls[0] = *(const float4*)(lc + c0);
    *(float4*)&ls[4] = *(const float4*)(lc + c0 + 4);
    *(float4*)&gs[0] = *(const float4*)(gb + c0);
    *(float4*)&gs[4] = *(const float4*)(gb + c0 + 4);
    #pragma unroll
    for (int jj = 0; jj < 8; ++jj) {
      float s = __expf(bf2f(xs[jj])) / ls[jj];
      float t = (s * (1.f - gs[jj]) + gs[jj] * (1.f / 2048.f)) * 0.03608439182435161f;
      float e = __expf(t);
      ev[j][jj] = e;
      psum += e;
    }
  }
  #pragma unroll
  for (int off = 1; off < 64; off <<= 1) psum += __shfl_xor(psum, off);
  const float inv = 1.f / psum;
  #pragma unroll
  for (int j = 0; j < 4; ++j) {
    const int c0 = j * 512 + lane * 8;
    float4 o0, o1;
    o0.x = ev[j][0] * inv; o0.y = ev[j][1] * inv; o0.z = ev[j][2] * inv; o0.w = ev[j][3] * inv;
    o1.x = ev[j][4] * inv; o1.y = ev[j][5] * inv; o1.z = ev[j][6] * inv; o1.w = ev[j][7] * inv;
    *(float4*)(wrow + c0) = o0;
    *(float4*)(wrow + c0 + 4) = o1;
    ushort4 b0, b1v;
    b0.x = f2bf(o0.x); b0.y = f2bf(o0.y); b0.z = f2bf(o0.z); b0.w = f2bf(o0.w);
    b1v.x = f2bf(o1.x); b1v.y = f2bf(o1.y); b1v.z = f2bf(o1.z); b1v.w = f2bf(o1.w);
    *(ushort4*)(wbrow + c0) = b0;
    *(ushort4*)(wbrow + c0 + 4) = b1v;
  }
}

// Fallback rowpass (no wb copy) — only if ws too small.
__global__ __launch_bounds__(256)
void rowpass_slow(float* __restrict__ w, const float* __restrict__ lcol,
                  const float* __restrict__ gg)
{
  const size_t row = blockIdx.x;
  const int b = (int)(row >> 11);
  const unsigned short* p = (const unsigned short*)w + row * 4096;
  float* wrow = w + row * 2048;
  const int c0 = threadIdx.x * 8;
  const float* lc = lcol + (b << 11);
  const float* gb = gg + (b << 11);

  unsigned short xs[8];
  *(ushort4*)&xs[0] = *(const ushort4*)(p + c0);
  *(ushort4*)&xs[4] = *(const ushort4*)(p + c0 + 4);
  float ls[8], gs[8];
  *(float4*)&ls[0] = *(const float4*)(lc + c0);
  *(float4*)&ls[4] = *(const float4*)(lc + c0 + 4);
  *(float4*)&gs[0] = *(const float4*)(gb + c0);
  *(float4*)&gs[4] = *(const float4*)(gb + c0 + 4);

  float e[8];
  float psum = 0.f;
  #pragma unroll
  for (int j = 0; j < 8; ++j) {
    float s = __expf(bf2f(xs[j])) / ls[j];
    float t = (s * (1.f - gs[j]) + gs[j] * (1.f / 2048.f)) * 0.03608439182435161f;
    float evv = __expf(t);
    e[j] = evv;
    psum += evv;
  }
  #pragma unroll
  for (int off = 1; off < 64; off <<= 1) psum += __shfl_xor(psum, off);
  __shared__ float red[4];
  if ((threadIdx.x & 63) == 0) red[threadIdx.x >> 6] = psum;
  __syncthreads();
  float inv = 1.f / (red[0] + red[1] + red[2] + red[3]);
  float4 o0, o1;
  o0.x = e[0] * inv; o0.y = e[1] * inv; o0.z = e[2] * inv; o0.w = e[3] * inv;
  o1.x = e[4] * inv; o1.y = e[5] * inv; o1.z = e[6] * inv; o1.w = e[7] * inv;
  *(float4*)(wrow + c0) = o0;
  *(float4*)(wrow + c0 + 4) = o1;
}

extern "C" void kernel_launch(void* const* d_in, const int* in_sizes, int n_in,
                              void* d_out, int out_size, void* d_ws, size_t ws_size,
                              hipStream_t stream)
{
  (void)in_sizes; (void)n_in; (void)out_size;
  const float* q  = (const float*)d_in[0];
  const float* k  = (const float*)d_in[1];
  const float* v  = (const float*)d_in[2];
  const float* W1 = (const float*)d_in[3];
  const float* b1 = (const float*)d_in[4];
  const float* W2 = (const float*)d_in[5];
  const float* b2 = (const float*)d_in[6];

  float* out0 = (float*)d_out;                       // [B,S,D] f32 (holds qb until PV)
  float* wbuf = out0 + (size_t)BATCH * SEQ * DIM;    // [B,S,S] f32 weights slots
  unsigned short* wsl = (unsigned short*)wbuf;       // slot view (lower: scores, upper: kb/vb)
  unsigned short* qb  = (unsigned short*)out0;

  float* g    = (float*)d_ws;                        // 16384
  float* lcol = g + 16384;                           // 16384
  float* pg   = lcol + 16384;                        // 65536 (4 used)
  float* pl   = pg + 65536;                          // 262144 (8*16384 used)
  unsigned short* W1T = (unsigned short*)(pl + 262144);            // 393216 ushorts
  unsigned short* vT  = (unsigned short*)((char*)d_ws + 2228224);  // 12.58M ushorts
  unsigned short* wb  = vT + (size_t)12582912;                     // 33.55M ushorts
  const bool fast = ws_size >= 94502912ull;

  prepack_all<<<3168, 256, 0, stream>>>(q, k, v, qb, wsl, vT, W1, W1T, fast ? 1 : 0);

  // gate: 8-phase 256x128, grid 256 (1 exact round) -> pg[4][16384]
  gemm_gate8<<<256, 512, 0, stream>>>(wsl + 2816, W1T, b1, W2, pg);
  // scores: 8-phase 256^2 -> bf16 into weight-row slots + column exp-sum partials
  gemm8<1><<<512, 512, 0, stream>>>(qb, wsl, nullptr, wbuf, nullptr, nullptr, nullptr, pl);

  finalize<<<64, 256, 0, stream>>>(pl, pg, b2, lcol, g);

  if (fast) {
    rowpass2<<<2048, 512, 0, stream>>>(wbuf, lcol, g, wb);
    // PV: 4-phase 128x192, grid 512, 2 blocks/CU
    gemm_pv<<<512, 512, 0, stream>>>(wb, vT, q, out0);
  } else {
    rowpass_slow<<<16384, 256, 0, stream>>>(wbuf, lcol, g);
    gemm_slow<<<dim3(6, 16, 8), 256, 0, stream>>>(wbuf, v, q, out0);
  }
}